// Round 1
// baseline (3989.655 us; speedup 1.0000x reference)
//
#include <hip/hip_runtime.h>

#define T_ 128
#define B_ 4096
#define N_ (T_*B_)
#define H_ 128
#define FEAT_ 96
#define K_ 224
#define G4H_ 512

__device__ __forceinline__ float fsig(float x) {
    float e = __builtin_amdgcn_exp2f(-1.44269504088896340736f * x);
    return __builtin_amdgcn_rcpf(1.0f + e);
}
__device__ __forceinline__ float ftanh(float x) {
    // tanh(x) = 2/(1+exp(-2x)) - 1
    float e = __builtin_amdgcn_exp2f(-2.88539008177792681472f * x);
    return fmaf(2.0f, __builtin_amdgcn_rcpf(1.0f + e), -1.0f);
}

#define FMA_ROW(accrow, a, w0, w1, w2, w3)                                              \
    accrow[0] = fmaf(a.x, w0.x, fmaf(a.y, w1.x, fmaf(a.z, w2.x, fmaf(a.w, w3.x, accrow[0])))); \
    accrow[1] = fmaf(a.x, w0.y, fmaf(a.y, w1.y, fmaf(a.z, w2.y, fmaf(a.w, w3.y, accrow[1])))); \
    accrow[2] = fmaf(a.x, w0.z, fmaf(a.y, w1.z, fmaf(a.z, w2.z, fmaf(a.w, w3.z, accrow[2])))); \
    accrow[3] = fmaf(a.x, w0.w, fmaf(a.y, w1.w, fmaf(a.z, w2.w, fmaf(a.w, w3.w, accrow[3]))));

// Build Wt[224][512]: Wt[k][g] = k<96 ? Wih[g][k] : Whh[g][k-96]; bias[g]=bih+bhh
__global__ __launch_bounds__(256) void prep_kernel(
    const float* __restrict__ Wih, const float* __restrict__ Whh,
    const float* __restrict__ bih, const float* __restrict__ bhh,
    float* __restrict__ Wt, float* __restrict__ bias)
{
    int idx = blockIdx.x * 256 + threadIdx.x;
    if (idx < K_ * G4H_) {
        int k = idx >> 9;
        int g = idx & 511;
        Wt[idx] = (k < FEAT_) ? Wih[g * FEAT_ + k] : Whh[g * H_ + (k - FEAT_)];
    }
    if (idx < G4H_) bias[idx] = bih[idx] + bhh[idx];
}

// Encoder: 32 samples/block, 256 threads. MLP 25->256->256->128->32 + loc/energy.
__global__ __launch_bounds__(256) void enc_kernel(
    const float* __restrict__ image, const float* __restrict__ location,
    const float* __restrict__ energy,
    const float* __restrict__ W1, const float* __restrict__ b1,
    const float* __restrict__ W2, const float* __restrict__ b2,
    const float* __restrict__ W3, const float* __restrict__ b3,
    const float* __restrict__ W4, const float* __restrict__ b4,
    const float* __restrict__ Wl, const float* __restrict__ bl,
    const float* __restrict__ We, const float* __restrict__ be,
    float* __restrict__ feats)
{
    __shared__ float bufA[32][256];
    __shared__ float bufB[32][256];
    const int tid = threadIdx.x;
    const int n0 = blockIdx.x * 32;

    // stage x = image/255 into bufB[:,0:25] (800 contiguous floats, coalesced)
    for (int idx = tid; idx < 32 * 25; idx += 256) {
        float v = image[(size_t)n0 * 25 + idx] * (1.0f / 255.0f);
        bufB[idx / 25][idx % 25] = v;
    }
    __syncthreads();

    const int tx = tid & 63;
    const int ty = tid >> 6;
    const int s0 = ty * 8;

    // ---- L1: 25 -> 256 relu : bufB -> bufA
    {
        const int j = tx * 4;
        float acc[8][4];
        const float4 bb = *(const float4*)(b1 + j);
        #pragma unroll
        for (int s = 0; s < 8; s++) { acc[s][0] = bb.x; acc[s][1] = bb.y; acc[s][2] = bb.z; acc[s][3] = bb.w; }
        for (int k = 0; k < 25; k++) {
            const float4 w = *(const float4*)(W1 + k * 256 + j);
            #pragma unroll
            for (int s = 0; s < 8; s++) {
                const float a = bufB[s0 + s][k];
                acc[s][0] = fmaf(a, w.x, acc[s][0]);
                acc[s][1] = fmaf(a, w.y, acc[s][1]);
                acc[s][2] = fmaf(a, w.z, acc[s][2]);
                acc[s][3] = fmaf(a, w.w, acc[s][3]);
            }
        }
        __syncthreads();  // everyone done reading bufB before L2 overwrites? (L1 writes bufA only; keep barrier for write ordering below)
        #pragma unroll
        for (int s = 0; s < 8; s++) {
            float4 v;
            v.x = fmaxf(acc[s][0], 0.f); v.y = fmaxf(acc[s][1], 0.f);
            v.z = fmaxf(acc[s][2], 0.f); v.w = fmaxf(acc[s][3], 0.f);
            *(float4*)&bufA[s0 + s][j] = v;
        }
    }
    __syncthreads();

    // ---- L2: 256 -> 256 relu : bufA -> bufB
    {
        const int j = tx * 4;
        float acc[8][4];
        const float4 bb = *(const float4*)(b2 + j);
        #pragma unroll
        for (int s = 0; s < 8; s++) { acc[s][0] = bb.x; acc[s][1] = bb.y; acc[s][2] = bb.z; acc[s][3] = bb.w; }
        for (int k = 0; k < 256; k += 4) {
            const float4 w0 = *(const float4*)(W2 + (k + 0) * 256 + j);
            const float4 w1 = *(const float4*)(W2 + (k + 1) * 256 + j);
            const float4 w2 = *(const float4*)(W2 + (k + 2) * 256 + j);
            const float4 w3 = *(const float4*)(W2 + (k + 3) * 256 + j);
            #pragma unroll
            for (int s = 0; s < 8; s++) {
                const float4 a = *(const float4*)&bufA[s0 + s][k];
                FMA_ROW(acc[s], a, w0, w1, w2, w3);
            }
        }
        __syncthreads();
        #pragma unroll
        for (int s = 0; s < 8; s++) {
            float4 v;
            v.x = fmaxf(acc[s][0], 0.f); v.y = fmaxf(acc[s][1], 0.f);
            v.z = fmaxf(acc[s][2], 0.f); v.w = fmaxf(acc[s][3], 0.f);
            *(float4*)&bufB[s0 + s][j] = v;
        }
    }
    __syncthreads();

    // ---- L3: 256 -> 128 relu : bufB -> bufA (2 cols/thread)
    {
        const int j = tx * 2;
        float acc[8][2];
        const float2 bb = *(const float2*)(b3 + j);
        #pragma unroll
        for (int s = 0; s < 8; s++) { acc[s][0] = bb.x; acc[s][1] = bb.y; }
        for (int k = 0; k < 256; k += 4) {
            const float2 w0 = *(const float2*)(W3 + (k + 0) * 128 + j);
            const float2 w1 = *(const float2*)(W3 + (k + 1) * 128 + j);
            const float2 w2 = *(const float2*)(W3 + (k + 2) * 128 + j);
            const float2 w3 = *(const float2*)(W3 + (k + 3) * 128 + j);
            #pragma unroll
            for (int s = 0; s < 8; s++) {
                const float4 a = *(const float4*)&bufB[s0 + s][k];
                acc[s][0] = fmaf(a.x, w0.x, fmaf(a.y, w1.x, fmaf(a.z, w2.x, fmaf(a.w, w3.x, acc[s][0]))));
                acc[s][1] = fmaf(a.x, w0.y, fmaf(a.y, w1.y, fmaf(a.z, w2.y, fmaf(a.w, w3.y, acc[s][1]))));
            }
        }
        __syncthreads();
        #pragma unroll
        for (int s = 0; s < 8; s++) {
            float2 v;
            v.x = fmaxf(acc[s][0], 0.f); v.y = fmaxf(acc[s][1], 0.f);
            *(float2*)&bufA[s0 + s][j] = v;
        }
    }
    __syncthreads();

    // ---- epilogue: L4 (128->32, relu) + loc + energy -> feats[n][96]
    for (int r = 0; r < 3; r++) {
        const int idx = tid + 256 * r;       // 0..767  (768 = 32 samples * 24 quad-groups)
        const int s = idx / 24;
        const int jg = idx % 24;
        float4 res;
        if (jg < 8) {
            const int j4 = jg * 4;
            float4 acc = *(const float4*)(b4 + j4);
            for (int k = 0; k < 128; k++) {
                const float a = bufA[s][k];
                const float4 w = *(const float4*)(W4 + k * 32 + j4);
                acc.x = fmaf(a, w.x, acc.x); acc.y = fmaf(a, w.y, acc.y);
                acc.z = fmaf(a, w.z, acc.z); acc.w = fmaf(a, w.w, acc.w);
            }
            res.x = fmaxf(acc.x, 0.f); res.y = fmaxf(acc.y, 0.f);
            res.z = fmaxf(acc.z, 0.f); res.w = fmaxf(acc.w, 0.f);
        } else if (jg < 16) {
            const int jj = (jg - 8) * 4;
            const float lx = location[(size_t)(n0 + s) * 2 + 0] * (1.0f / 10.0f);
            const float ly = location[(size_t)(n0 + s) * 2 + 1] * (1.0f / 10.0f);
            const float4 w0 = *(const float4*)(Wl + jj);
            const float4 w1 = *(const float4*)(Wl + 32 + jj);
            const float4 bb = *(const float4*)(bl + jj);
            res.x = fmaf(lx, w0.x, fmaf(ly, w1.x, bb.x));
            res.y = fmaf(lx, w0.y, fmaf(ly, w1.y, bb.y));
            res.z = fmaf(lx, w0.z, fmaf(ly, w1.z, bb.z));
            res.w = fmaf(lx, w0.w, fmaf(ly, w1.w, bb.w));
        } else {
            const int jj = (jg - 16) * 4;
            const float e = energy[n0 + s] * (1.0f / 200.0f);
            const float4 w = *(const float4*)(We + jj);
            const float4 bb = *(const float4*)(be + jj);
            res.x = fmaf(e, w.x, bb.x);
            res.y = fmaf(e, w.y, bb.y);
            res.z = fmaf(e, w.z, bb.z);
            res.w = fmaf(e, w.w, bb.w);
        }
        *(float4*)(feats + (size_t)(n0 + s) * FEAT_ + jg * 4) = res;
    }
}

// LSTM + heads: 256 blocks x 512 threads; block owns 16 batch rows for all T steps.
__global__ __launch_bounds__(512) void lstm_kernel(
    const float* __restrict__ feats, const int* __restrict__ done,
    const float* __restrict__ h0, const float* __restrict__ c0,
    const float* __restrict__ Wt, const float* __restrict__ bias,
    const float* __restrict__ Wa, const float* __restrict__ ba,
    const float* __restrict__ Wc, const float* __restrict__ bc,
    float* __restrict__ out)
{
    // A row padded to 228 (224%32==0 would put the head dot's strided reads all in one bank)
    __shared__ float A[16][228];        // [s][0:96]=x_t, [s][96:224]=h
    __shared__ float gates[16][512];
    __shared__ float Whd[128][7];
    __shared__ float bhd[8];
    const int tid = threadIdx.x;
    const int r0 = blockIdx.x * 16;

    for (int idx = tid; idx < 128 * 7; idx += 512) {
        int k = idx / 7, j = idx % 7;
        Whd[k][j] = (j < 6) ? Wa[k * 6 + j] : Wc[k];
    }
    if (tid < 7) bhd[tid] = (tid < 6) ? ba[tid] : bc[0];

    // owner mapping: thread owns 4 hidden units of one sample
    const int os = tid >> 5;            // sample 0..15
    const int ou = (tid * 4) & 127;     // unit base
    float4 c = *(const float4*)(c0 + (size_t)(r0 + os) * H_ + ou);
    *(float4*)&A[os][96 + ou] = *(const float4*)(h0 + (size_t)(r0 + os) * H_ + ou);

    // GEMM mapping: 4 samples x 4 gate-cols per thread
    const int tx = tid & 127;
    const int ty = tid >> 7;
    const int gj = tx * 4;
    const int gs0 = ty * 4;
    const float4 bias4 = *(const float4*)(bias + gj);

    for (int t = 0; t < T_; t++) {
        // stage x_t (16x96 floats, contiguous -> coalesced float4)
        if (tid < 384) {
            const int s = tid / 24, cc = (tid % 24) * 4;
            *(float4*)&A[s][cc] = *(const float4*)(feats + (size_t)(t * B_ + r0 + s) * FEAT_ + cc);
        }
        // done-mask h and c (owners; h region disjoint from x staging region)
        const float m = 1.0f - (float)done[t * B_ + r0 + os];
        c.x *= m; c.y *= m; c.z *= m; c.w *= m;
        float4 hv = *(const float4*)&A[os][96 + ou];
        hv.x *= m; hv.y *= m; hv.z *= m; hv.w *= m;
        *(float4*)&A[os][96 + ou] = hv;
        __syncthreads();

        // gates[16][512] = A[16][224] @ Wt[224][512] + bias
        float acc[4][4];
        #pragma unroll
        for (int s = 0; s < 4; s++) { acc[s][0] = bias4.x; acc[s][1] = bias4.y; acc[s][2] = bias4.z; acc[s][3] = bias4.w; }
        for (int k = 0; k < K_; k += 4) {
            const float4 w0 = *(const float4*)(Wt + (size_t)(k + 0) * G4H_ + gj);
            const float4 w1 = *(const float4*)(Wt + (size_t)(k + 1) * G4H_ + gj);
            const float4 w2 = *(const float4*)(Wt + (size_t)(k + 2) * G4H_ + gj);
            const float4 w3 = *(const float4*)(Wt + (size_t)(k + 3) * G4H_ + gj);
            #pragma unroll
            for (int s = 0; s < 4; s++) {
                const float4 a = *(const float4*)&A[gs0 + s][k];
                FMA_ROW(acc[s], a, w0, w1, w2, w3);
            }
        }
        #pragma unroll
        for (int s = 0; s < 4; s++) {
            float4 v; v.x = acc[s][0]; v.y = acc[s][1]; v.z = acc[s][2]; v.w = acc[s][3];
            *(float4*)&gates[gs0 + s][gj] = v;
        }
        __syncthreads();

        // elementwise LSTM cell (owners)
        {
            const float4 gi = *(const float4*)&gates[os][ou];
            const float4 gf = *(const float4*)&gates[os][128 + ou];
            const float4 gg = *(const float4*)&gates[os][256 + ou];
            const float4 go = *(const float4*)&gates[os][384 + ou];
            c.x = fsig(gf.x) * c.x + fsig(gi.x) * ftanh(gg.x);
            c.y = fsig(gf.y) * c.y + fsig(gi.y) * ftanh(gg.y);
            c.z = fsig(gf.z) * c.z + fsig(gi.z) * ftanh(gg.z);
            c.w = fsig(gf.w) * c.w + fsig(gi.w) * ftanh(gg.w);
            float4 hn;
            hn.x = fsig(go.x) * ftanh(c.x);
            hn.y = fsig(go.y) * ftanh(c.y);
            hn.z = fsig(go.z) * ftanh(c.z);
            hn.w = fsig(go.w) * ftanh(c.w);
            *(float4*)&A[os][96 + ou] = hn;
        }
        __syncthreads();

        // heads: 16 samples x 7 outputs, dot over H=128
        if (tid < 112) {
            const int s = tid / 7, jj = tid % 7;
            float acch = bhd[jj];
            for (int k = 0; k < 128; k++)
                acch = fmaf(A[s][96 + k], Whd[k][jj], acch);
            out[((size_t)t * B_ + r0 + s) * 7 + jj] = acch;
        }
        __syncthreads();
    }
}

extern "C" void kernel_launch(void* const* d_in, const int* in_sizes, int n_in,
                              void* d_out, int out_size, void* d_ws, size_t ws_size,
                              hipStream_t stream) {
    const float* image    = (const float*)d_in[0];
    const float* location = (const float*)d_in[1];
    const float* energy   = (const float*)d_in[2];
    const int*   done     = (const int*)d_in[3];
    const float* h0       = (const float*)d_in[4];
    const float* c0       = (const float*)d_in[5];
    const float* W1 = (const float*)d_in[6];   const float* b1 = (const float*)d_in[7];
    const float* W2 = (const float*)d_in[8];   const float* b2 = (const float*)d_in[9];
    const float* W3 = (const float*)d_in[10];  const float* b3 = (const float*)d_in[11];
    const float* W4 = (const float*)d_in[12];  const float* b4 = (const float*)d_in[13];
    const float* Wl = (const float*)d_in[14];  const float* bl = (const float*)d_in[15];
    const float* We = (const float*)d_in[16];  const float* be = (const float*)d_in[17];
    const float* Wih = (const float*)d_in[18]; const float* Whh = (const float*)d_in[19];
    const float* bih = (const float*)d_in[20]; const float* bhh = (const float*)d_in[21];
    const float* Wa = (const float*)d_in[22];  const float* ba = (const float*)d_in[23];
    const float* Wc = (const float*)d_in[24];  const float* bc = (const float*)d_in[25];

    float* ws   = (float*)d_ws;
    float* Wt   = ws;                         // 224*512
    float* bias = ws + K_ * G4H_;             // 512
    float* feats = ws + K_ * G4H_ + G4H_;     // N*96 (16B-aligned: 115200 floats offset)
    float* out  = (float*)d_out;

    prep_kernel<<<(K_ * G4H_ + 255) / 256, 256, 0, stream>>>(Wih, Whh, bih, bhh, Wt, bias);
    enc_kernel<<<N_ / 32, 256, 0, stream>>>(image, location, energy,
                                            W1, b1, W2, b2, W3, b3, W4, b4,
                                            Wl, bl, We, be, feats);
    lstm_kernel<<<B_ / 16, 512, 0, stream>>>(feats, done, h0, c0, Wt, bias,
                                             Wa, ba, Wc, bc, out);
}

// Round 2
// 2244.383 us; speedup vs baseline: 1.7776x; 1.7776x over previous
//
#include <hip/hip_runtime.h>

#define T_ 128
#define B_ 4096
#define N_ (T_*B_)
#define H_ 128
#define FEAT_ 96
#define K_ 224
#define G4H_ 512

typedef __attribute__((ext_vector_type(8))) short short8;   // 8 bf16 = 4 VGPRs
typedef __attribute__((ext_vector_type(4))) float f32x4;

__device__ __forceinline__ float fsig(float x) {
    float e = __builtin_amdgcn_exp2f(-1.44269504088896340736f * x);
    return __builtin_amdgcn_rcpf(1.0f + e);
}
__device__ __forceinline__ float ftanh(float x) {
    float e = __builtin_amdgcn_exp2f(-2.88539008177792681472f * x);
    return fmaf(2.0f, __builtin_amdgcn_rcpf(1.0f + e), -1.0f);
}
__device__ __forceinline__ short f2bf(float f) {
    unsigned u = __builtin_bit_cast(unsigned, f);
    u += 0x7fff + ((u >> 16) & 1);              // RNE
    return (short)(u >> 16);
}

#define FMA_ROW(accrow, a, w0, w1, w2, w3)                                              \
    accrow[0] = fmaf(a.x, w0.x, fmaf(a.y, w1.x, fmaf(a.z, w2.x, fmaf(a.w, w3.x, accrow[0])))); \
    accrow[1] = fmaf(a.x, w0.y, fmaf(a.y, w1.y, fmaf(a.z, w2.y, fmaf(a.w, w3.y, accrow[1])))); \
    accrow[2] = fmaf(a.x, w0.z, fmaf(a.y, w1.z, fmaf(a.z, w2.z, fmaf(a.w, w3.z, accrow[2])))); \
    accrow[3] = fmaf(a.x, w0.w, fmaf(a.y, w1.w, fmaf(a.z, w2.w, fmaf(a.w, w3.w, accrow[3]))));

// Pack combined Wt[k][g] (k<96: Wih, else Whh) into bf16 B-fragment order:
// Wtp[((n*7+kk)*64 + lane)*8 + j] = bf16(Wt[kk*32 + (lane>>4)*8 + j][n*16 + (lane&15)])
__global__ __launch_bounds__(256) void prep_kernel(
    const float* __restrict__ Wih, const float* __restrict__ Whh,
    const float* __restrict__ bih, const float* __restrict__ bhh,
    short* __restrict__ Wtp, float* __restrict__ bias)
{
    int idx = blockIdx.x * 256 + threadIdx.x;
    if (idx < K_ * G4H_) {
        int j = idx & 7;
        int L = (idx >> 3) & 63;
        int r = idx >> 9;              // n*7 + kk, 0..223
        int kk = r % 7, n = r / 7;
        int k = kk * 32 + ((L >> 4) << 3) + j;
        int g = (n << 4) + (L & 15);
        float v = (k < FEAT_) ? Wih[g * FEAT_ + k] : Whh[g * H_ + (k - FEAT_)];
        Wtp[idx] = f2bf(v);
    }
    if (idx < G4H_) bias[idx] = bih[idx] + bhh[idx];
}

// Encoder: unchanged fp32 register-tiled MLP (MFMA rewrite next round).
__global__ __launch_bounds__(256) void enc_kernel(
    const float* __restrict__ image, const float* __restrict__ location,
    const float* __restrict__ energy,
    const float* __restrict__ W1, const float* __restrict__ b1,
    const float* __restrict__ W2, const float* __restrict__ b2,
    const float* __restrict__ W3, const float* __restrict__ b3,
    const float* __restrict__ W4, const float* __restrict__ b4,
    const float* __restrict__ Wl, const float* __restrict__ bl,
    const float* __restrict__ We, const float* __restrict__ be,
    float* __restrict__ feats)
{
    __shared__ float bufA[32][256];
    __shared__ float bufB[32][256];
    const int tid = threadIdx.x;
    const int n0 = blockIdx.x * 32;

    for (int idx = tid; idx < 32 * 25; idx += 256) {
        float v = image[(size_t)n0 * 25 + idx] * (1.0f / 255.0f);
        bufB[idx / 25][idx % 25] = v;
    }
    __syncthreads();

    const int tx = tid & 63;
    const int ty = tid >> 6;
    const int s0 = ty * 8;

    {   // L1: 25 -> 256
        const int j = tx * 4;
        float acc[8][4];
        const float4 bb = *(const float4*)(b1 + j);
        #pragma unroll
        for (int s = 0; s < 8; s++) { acc[s][0] = bb.x; acc[s][1] = bb.y; acc[s][2] = bb.z; acc[s][3] = bb.w; }
        for (int k = 0; k < 25; k++) {
            const float4 w = *(const float4*)(W1 + k * 256 + j);
            #pragma unroll
            for (int s = 0; s < 8; s++) {
                const float a = bufB[s0 + s][k];
                acc[s][0] = fmaf(a, w.x, acc[s][0]);
                acc[s][1] = fmaf(a, w.y, acc[s][1]);
                acc[s][2] = fmaf(a, w.z, acc[s][2]);
                acc[s][3] = fmaf(a, w.w, acc[s][3]);
            }
        }
        __syncthreads();
        #pragma unroll
        for (int s = 0; s < 8; s++) {
            float4 v;
            v.x = fmaxf(acc[s][0], 0.f); v.y = fmaxf(acc[s][1], 0.f);
            v.z = fmaxf(acc[s][2], 0.f); v.w = fmaxf(acc[s][3], 0.f);
            *(float4*)&bufA[s0 + s][j] = v;
        }
    }
    __syncthreads();

    {   // L2: 256 -> 256
        const int j = tx * 4;
        float acc[8][4];
        const float4 bb = *(const float4*)(b2 + j);
        #pragma unroll
        for (int s = 0; s < 8; s++) { acc[s][0] = bb.x; acc[s][1] = bb.y; acc[s][2] = bb.z; acc[s][3] = bb.w; }
        for (int k = 0; k < 256; k += 4) {
            const float4 w0 = *(const float4*)(W2 + (k + 0) * 256 + j);
            const float4 w1 = *(const float4*)(W2 + (k + 1) * 256 + j);
            const float4 w2 = *(const float4*)(W2 + (k + 2) * 256 + j);
            const float4 w3 = *(const float4*)(W2 + (k + 3) * 256 + j);
            #pragma unroll
            for (int s = 0; s < 8; s++) {
                const float4 a = *(const float4*)&bufA[s0 + s][k];
                FMA_ROW(acc[s], a, w0, w1, w2, w3);
            }
        }
        __syncthreads();
        #pragma unroll
        for (int s = 0; s < 8; s++) {
            float4 v;
            v.x = fmaxf(acc[s][0], 0.f); v.y = fmaxf(acc[s][1], 0.f);
            v.z = fmaxf(acc[s][2], 0.f); v.w = fmaxf(acc[s][3], 0.f);
            *(float4*)&bufB[s0 + s][j] = v;
        }
    }
    __syncthreads();

    {   // L3: 256 -> 128
        const int j = tx * 2;
        float acc[8][2];
        const float2 bb = *(const float2*)(b3 + j);
        #pragma unroll
        for (int s = 0; s < 8; s++) { acc[s][0] = bb.x; acc[s][1] = bb.y; }
        for (int k = 0; k < 256; k += 4) {
            const float2 w0 = *(const float2*)(W3 + (k + 0) * 128 + j);
            const float2 w1 = *(const float2*)(W3 + (k + 1) * 128 + j);
            const float2 w2 = *(const float2*)(W3 + (k + 2) * 128 + j);
            const float2 w3 = *(const float2*)(W3 + (k + 3) * 128 + j);
            #pragma unroll
            for (int s = 0; s < 8; s++) {
                const float4 a = *(const float4*)&bufB[s0 + s][k];
                acc[s][0] = fmaf(a.x, w0.x, fmaf(a.y, w1.x, fmaf(a.z, w2.x, fmaf(a.w, w3.x, acc[s][0]))));
                acc[s][1] = fmaf(a.x, w0.y, fmaf(a.y, w1.y, fmaf(a.z, w2.y, fmaf(a.w, w3.y, acc[s][1]))));
            }
        }
        __syncthreads();
        #pragma unroll
        for (int s = 0; s < 8; s++) {
            float2 v;
            v.x = fmaxf(acc[s][0], 0.f); v.y = fmaxf(acc[s][1], 0.f);
            *(float2*)&bufA[s0 + s][j] = v;
        }
    }
    __syncthreads();

    // epilogue: L4 + loc + energy
    for (int r = 0; r < 3; r++) {
        const int idx = tid + 256 * r;
        const int s = idx / 24;
        const int jg = idx % 24;
        float4 res;
        if (jg < 8) {
            const int j4 = jg * 4;
            float4 acc = *(const float4*)(b4 + j4);
            for (int k = 0; k < 128; k++) {
                const float a = bufA[s][k];
                const float4 w = *(const float4*)(W4 + k * 32 + j4);
                acc.x = fmaf(a, w.x, acc.x); acc.y = fmaf(a, w.y, acc.y);
                acc.z = fmaf(a, w.z, acc.z); acc.w = fmaf(a, w.w, acc.w);
            }
            res.x = fmaxf(acc.x, 0.f); res.y = fmaxf(acc.y, 0.f);
            res.z = fmaxf(acc.z, 0.f); res.w = fmaxf(acc.w, 0.f);
        } else if (jg < 16) {
            const int jj = (jg - 8) * 4;
            const float lx = location[(size_t)(n0 + s) * 2 + 0] * (1.0f / 10.0f);
            const float ly = location[(size_t)(n0 + s) * 2 + 1] * (1.0f / 10.0f);
            const float4 w0 = *(const float4*)(Wl + jj);
            const float4 w1 = *(const float4*)(Wl + 32 + jj);
            const float4 bb = *(const float4*)(bl + jj);
            res.x = fmaf(lx, w0.x, fmaf(ly, w1.x, bb.x));
            res.y = fmaf(lx, w0.y, fmaf(ly, w1.y, bb.y));
            res.z = fmaf(lx, w0.z, fmaf(ly, w1.z, bb.z));
            res.w = fmaf(lx, w0.w, fmaf(ly, w1.w, bb.w));
        } else {
            const int jj = (jg - 16) * 4;
            const float e = energy[n0 + s] * (1.0f / 200.0f);
            const float4 w = *(const float4*)(We + jj);
            const float4 bb = *(const float4*)(be + jj);
            res.x = fmaf(e, w.x, bb.x);
            res.y = fmaf(e, w.y, bb.y);
            res.z = fmaf(e, w.z, bb.z);
            res.w = fmaf(e, w.w, bb.w);
        }
        *(float4*)(feats + (size_t)(n0 + s) * FEAT_ + jg * 4) = res;
    }
}

// MFMA LSTM: 256 blocks x 512 thr (8 waves). Block owns 16 samples for all T.
// Wave w owns N-tiles {w, w+8, w+16, w+24} = gates i,f,g,o for units w*16+(lane&15):
// cell update is fully in-register. Tiles n<16 held in LDS; n>=16: kk==0 held, rest L2.
__global__ __launch_bounds__(512) void lstm_kernel(
    const float* __restrict__ feats, const int* __restrict__ done,
    const float* __restrict__ h0, const float* __restrict__ c0,
    const short* __restrict__ Wtp, const float* __restrict__ bias,
    const float* __restrict__ Wa, const float* __restrict__ ba,
    const float* __restrict__ Wc, const float* __restrict__ bc,
    float* __restrict__ out)
{
#define AROW 232   // 16 rows x 232 bf16: [0:96]=x_t, [96:224]=h  (pad vs 224%32==0)
#define HROW 136   // unmasked h for heads
    __shared__ __align__(16) short A[16 * AROW];
    __shared__ __align__(16) short Hout[16 * HROW];
    __shared__ __align__(16) short HW[4 * 64 * 8];       // head B-frags
    __shared__ __align__(16) short WL[112 * 64 * 8];     // held frags, n<16 (112 KB)
    __shared__ __align__(16) short WL2[16 * 64 * 8];     // held frags, n>=16, kk==0 (16 KB)

    const int tid = threadIdx.x;
    const int r0 = blockIdx.x * 16;
    const int lane = tid & 63;
    const int wv = tid >> 6;            // wave 0..7
    const int col = lane & 15;
    const int quad = lane >> 4;
    const int u = (wv << 4) + col;      // owned unit 0..127

    // ---- init: copy held weight frags into LDS (src layout == dst layout)
    {
        const float4* src = (const float4*)Wtp;
        float4* dst = (float4*)WL;
        for (int i = tid; i < 112 * 64; i += 512) dst[i] = src[i];
        float4* dst2 = (float4*)WL2;
        for (int i = tid; i < 16 * 64; i += 512) {
            int fid = (16 + (i >> 6)) * 7;              // kk = 0
            dst2[i] = src[fid * 64 + (i & 63)];
        }
    }
    // head weight B-frags: B[k][n] with n<6 -> Wa, n==6 -> Wc, else 0
    for (int idx = tid; idx < 4 * 64 * 8; idx += 512) {
        int j = idx & 7, L = (idx >> 3) & 63, kk2 = idx >> 9;
        int k = kk2 * 32 + ((L >> 4) << 3) + j;
        int n = L & 15;
        float v = (n < 6) ? Wa[k * 6 + n] : (n == 6 ? Wc[k] : 0.0f);
        HW[idx] = f2bf(v);
    }
    // h0/c0 masked by done[0] (each thread writes its 4 owned (sample,unit) cells)
    f32x4 c;
    #pragma unroll
    for (int r = 0; r < 4; r++) {
        int s = (quad << 2) + r;
        float m = 1.0f - (float)done[r0 + s];
        c[r] = c0[(size_t)(r0 + s) * H_ + u] * m;
        float h = h0[(size_t)(r0 + s) * H_ + u] * m;
        A[s * AROW + 96 + u] = f2bf(h);
    }
    // stage x_0
    if (tid < 192) {
        int s = tid / 12, gp = tid % 12;
        const float* fp = feats + (size_t)(r0 + s) * FEAT_ + gp * 8;
        const float4 a0 = *(const float4*)fp;
        const float4 a1 = *(const float4*)(fp + 4);
        short8 v;
        v[0] = f2bf(a0.x); v[1] = f2bf(a0.y); v[2] = f2bf(a0.z); v[3] = f2bf(a0.w);
        v[4] = f2bf(a1.x); v[5] = f2bf(a1.y); v[6] = f2bf(a1.z); v[7] = f2bf(a1.w);
        *(short8*)&A[s * AROW + gp * 8] = v;
    }
    // per-thread gate biases (one per owned tile)
    const float bi0 = bias[((wv +  0) << 4) + col];
    const float bi1 = bias[((wv +  8) << 4) + col];
    const float bi2 = bias[((wv + 16) << 4) + col];
    const float bi3 = bias[((wv + 24) << 4) + col];
    const float hb = (col < 6) ? ba[col] : (col == 6 ? bc[0] : 0.0f);
    __syncthreads();

    for (int t = 0; t < T_; t++) {
        f32x4 acc0 = {bi0, bi0, bi0, bi0};   // i
        f32x4 acc1 = {bi1, bi1, bi1, bi1};   // f
        f32x4 acc2 = {bi2, bi2, bi2, bi2};   // g
        f32x4 acc3 = {bi3, bi3, bi3, bi3};   // o
        #pragma unroll
        for (int kk = 0; kk < 7; kk++) {
            const short8 af = *(const short8*)&A[col * AROW + kk * 32 + (quad << 3)];
            const short8 b0 = *(const short8*)&WL[(((wv + 0) * 7 + kk) * 64 + lane) * 8];
            const short8 b1 = *(const short8*)&WL[(((wv + 8) * 7 + kk) * 64 + lane) * 8];
            const short8 b2 = (kk == 0)
                ? *(const short8*)&WL2[(((wv + 0)) * 64 + lane) * 8]
                : *(const short8*)&Wtp[(size_t)((((wv + 16) * 7 + kk) * 64 + lane)) * 8];
            const short8 b3 = (kk == 0)
                ? *(const short8*)&WL2[(((wv + 8)) * 64 + lane) * 8]
                : *(const short8*)&Wtp[(size_t)((((wv + 24) * 7 + kk) * 64 + lane)) * 8];
            acc0 = __builtin_amdgcn_mfma_f32_16x16x32_bf16(af, b0, acc0, 0, 0, 0);
            acc1 = __builtin_amdgcn_mfma_f32_16x16x32_bf16(af, b1, acc1, 0, 0, 0);
            acc2 = __builtin_amdgcn_mfma_f32_16x16x32_bf16(af, b2, acc2, 0, 0, 0);
            acc3 = __builtin_amdgcn_mfma_f32_16x16x32_bf16(af, b3, acc3, 0, 0, 0);
        }
        // cell update in-register; pre-mask next state with done[t+1]
        f32x4 hm, hu;
        #pragma unroll
        for (int r = 0; r < 4; r++) {
            float ig = fsig(acc0[r]);
            float fg = fsig(acc1[r]);
            float gg = ftanh(acc2[r]);
            float og = fsig(acc3[r]);
            float cn = fmaf(fg, c[r], ig * gg);
            float h = og * ftanh(cn);
            float m = 1.0f;
            if (t < T_ - 1) m = 1.0f - (float)done[(size_t)(t + 1) * B_ + r0 + (quad << 2) + r];
            c[r] = cn * m;
            hm[r] = h * m;
            hu[r] = h;
        }
        __syncthreads();   // all waves finished reading A for this step's GEMM
        #pragma unroll
        for (int r = 0; r < 4; r++) {
            int s = (quad << 2) + r;
            A[s * AROW + 96 + u] = f2bf(hm[r]);
            Hout[s * HROW + u] = f2bf(hu[r]);
        }
        if (wv != 0 && t < T_ - 1) {       // waves 1-3 stage x_{t+1}; wave 0 does heads
            int w2 = tid - 64;
            if (w2 < 192) {
                int s = w2 / 12, gp = w2 % 12;
                const float* fp = feats + ((size_t)(t + 1) * B_ + r0 + s) * FEAT_ + gp * 8;
                const float4 a0 = *(const float4*)fp;
                const float4 a1 = *(const float4*)(fp + 4);
                short8 v;
                v[0] = f2bf(a0.x); v[1] = f2bf(a0.y); v[2] = f2bf(a0.z); v[3] = f2bf(a0.w);
                v[4] = f2bf(a1.x); v[5] = f2bf(a1.y); v[6] = f2bf(a1.z); v[7] = f2bf(a1.w);
                *(short8*)&A[s * AROW + gp * 8] = v;
            }
        }
        __syncthreads();   // h/x visible; Hout stable until wave0 re-joins next barrier
        if (wv == 0) {
            f32x4 ha = {hb, hb, hb, hb};
            #pragma unroll
            for (int kk2 = 0; kk2 < 4; kk2++) {
                const short8 hf = *(const short8*)&Hout[col * HROW + kk2 * 32 + (quad << 3)];
                const short8 wf = *(const short8*)&HW[(kk2 * 64 + lane) * 8];
                ha = __builtin_amdgcn_mfma_f32_16x16x32_bf16(hf, wf, ha, 0, 0, 0);
            }
            if (col < 7) {
                #pragma unroll
                for (int r = 0; r < 4; r++) {
                    int s = (quad << 2) + r;
                    out[((size_t)t * B_ + r0 + s) * 7 + col] = ha[r];
                }
            }
        }
    }
#undef AROW
#undef HROW
}

extern "C" void kernel_launch(void* const* d_in, const int* in_sizes, int n_in,
                              void* d_out, int out_size, void* d_ws, size_t ws_size,
                              hipStream_t stream) {
    const float* image    = (const float*)d_in[0];
    const float* location = (const float*)d_in[1];
    const float* energy   = (const float*)d_in[2];
    const int*   done     = (const int*)d_in[3];
    const float* h0       = (const float*)d_in[4];
    const float* c0       = (const float*)d_in[5];
    const float* W1 = (const float*)d_in[6];   const float* b1 = (const float*)d_in[7];
    const float* W2 = (const float*)d_in[8];   const float* b2 = (const float*)d_in[9];
    const float* W3 = (const float*)d_in[10];  const float* b3 = (const float*)d_in[11];
    const float* W4 = (const float*)d_in[12];  const float* b4 = (const float*)d_in[13];
    const float* Wl = (const float*)d_in[14];  const float* bl = (const float*)d_in[15];
    const float* We = (const float*)d_in[16];  const float* be = (const float*)d_in[17];
    const float* Wih = (const float*)d_in[18]; const float* Whh = (const float*)d_in[19];
    const float* bih = (const float*)d_in[20]; const float* bhh = (const float*)d_in[21];
    const float* Wa = (const float*)d_in[22];  const float* ba = (const float*)d_in[23];
    const float* Wc = (const float*)d_in[24];  const float* bc = (const float*)d_in[25];

    char* ws = (char*)d_ws;
    short* Wtp  = (short*)ws;                                  // 224*512 bf16 = 229376 B
    float* bias = (float*)(ws + 229376);                       // 512 f32
    float* feats = (float*)(ws + 229376 + 2048);               // N*96 f32 (16B aligned)
    float* out  = (float*)d_out;

    prep_kernel<<<(K_ * G4H_ + 255) / 256, 256, 0, stream>>>(Wih, Whh, bih, bhh, Wtp, bias);
    enc_kernel<<<N_ / 32, 256, 0, stream>>>(image, location, energy,
                                            W1, b1, W2, b2, W3, b3, W4, b4,
                                            Wl, bl, We, be, feats);
    lstm_kernel<<<B_ / 16, 512, 0, stream>>>(feats, done, h0, c0, Wtp, bias,
                                             Wa, ba, Wc, bc, out);
}

// Round 3
// 585.389 us; speedup vs baseline: 6.8154x; 3.8340x over previous
//
#include <hip/hip_runtime.h>

#define T_ 128
#define B_ 4096
#define N_ (T_*B_)
#define H_ 128
#define FEAT_ 96
#define K_ 224
#define G4H_ 512

typedef __attribute__((ext_vector_type(8))) short short8;   // 8 bf16 = 4 VGPRs
typedef __attribute__((ext_vector_type(4))) short short4v;  // 4 bf16 = 2 VGPRs
typedef __attribute__((ext_vector_type(4))) float f32x4;

__device__ __forceinline__ float fsig(float x) {
    float e = __builtin_amdgcn_exp2f(-1.44269504088896340736f * x);
    return __builtin_amdgcn_rcpf(1.0f + e);
}
__device__ __forceinline__ float ftanh(float x) {
    float e = __builtin_amdgcn_exp2f(-2.88539008177792681472f * x);
    return fmaf(2.0f, __builtin_amdgcn_rcpf(1.0f + e), -1.0f);
}
__device__ __forceinline__ short f2bf(float f) {
    unsigned u = __builtin_bit_cast(unsigned, f);
    u += 0x7fff + ((u >> 16) & 1);              // RNE
    return (short)(u >> 16);
}
__device__ __forceinline__ short4v pack4relu(const f32x4 a) {
    short4v v;
    v[0] = f2bf(fmaxf(a[0], 0.f)); v[1] = f2bf(fmaxf(a[1], 0.f));
    v[2] = f2bf(fmaxf(a[2], 0.f)); v[3] = f2bf(fmaxf(a[3], 0.f));
    return v;
}

// ---------------- prep: pack all weights into bf16 MFMA-fragment order ----------------
// Fragment formula (both A- and B-operand packs are identical):
//   P[((f)*64 + L)*8 + j] = bf16( W[k = kk*32 + (L>>4)*8 + j][out = nt*16 + (L&15)] )
// Regions: LSTM Wtp (224 frags), W1p (16), W2p (128), W3p (64), W4p (8), bias.
__global__ __launch_bounds__(256) void prep_kernel(
    const float* __restrict__ Wih, const float* __restrict__ Whh,
    const float* __restrict__ bih, const float* __restrict__ bhh,
    const float* __restrict__ W1, const float* __restrict__ W2,
    const float* __restrict__ W3, const float* __restrict__ W4,
    short* __restrict__ Wtp, float* __restrict__ bias,
    short* __restrict__ W1p, short* __restrict__ W2p,
    short* __restrict__ W3p, short* __restrict__ W4p)
{
    int idx = blockIdx.x * 256 + threadIdx.x;
    if (idx < 114688) {                     // LSTM combined [224][512]
        int j = idx & 7, L = (idx >> 3) & 63, r = idx >> 9;
        int kk = r % 7, n = r / 7;
        int k = kk * 32 + ((L >> 4) << 3) + j;
        int g = (n << 4) + (L & 15);
        float v = (k < FEAT_) ? Wih[g * FEAT_ + k] : Whh[g * H_ + (k - FEAT_)];
        Wtp[idx] = f2bf(v);
        return;
    }
    int e = idx - 114688;
    if (e < 8192) {                         // W1 [25,256], zero-pad k>=25
        int j = e & 7, L = (e >> 3) & 63, nt = e >> 9;
        int k = ((L >> 4) << 3) + j;
        int o = nt * 16 + (L & 15);
        W1p[e] = (k < 25) ? f2bf(W1[k * 256 + o]) : (short)0;
        return;
    }
    e -= 8192;
    if (e < 65536) {                        // W2 [256,256]
        int j = e & 7, L = (e >> 3) & 63, f = e >> 9;
        int kk = f & 7, nt = f >> 3;
        int k = kk * 32 + ((L >> 4) << 3) + j;
        W2p[e] = f2bf(W2[k * 256 + nt * 16 + (L & 15)]);
        return;
    }
    e -= 65536;
    if (e < 32768) {                        // W3 [256,128]
        int j = e & 7, L = (e >> 3) & 63, f = e >> 9;
        int kk = f & 7, nt = f >> 3;
        int k = kk * 32 + ((L >> 4) << 3) + j;
        W3p[e] = f2bf(W3[k * 128 + nt * 16 + (L & 15)]);
        return;
    }
    e -= 32768;
    if (e < 4096) {                         // W4 [128,32]
        int j = e & 7, L = (e >> 3) & 63, f = e >> 9;
        int kk = f & 3, nt = f >> 2;
        int k = kk * 32 + ((L >> 4) << 3) + j;
        W4p[e] = f2bf(W4[k * 32 + nt * 16 + (L & 15)]);
        return;
    }
    e -= 4096;
    if (e < 512) bias[e] = bih[e] + bhh[e];
}

// ---------------- MFMA encoder: 64 samples/block, 256 thr (4 waves) ----------------
// A operand = weights (m = out feature), B operand = activations (n = sample):
// C/D gives each thread 4 consecutive out-features of one sample -> packed short4 writes.
__global__ __launch_bounds__(256) void enc_kernel(
    const float* __restrict__ image, const float* __restrict__ location,
    const float* __restrict__ energy,
    const short* __restrict__ W1p, const float* __restrict__ b1,
    const short* __restrict__ W2p, const float* __restrict__ b2,
    const short* __restrict__ W3p, const float* __restrict__ b3,
    const short* __restrict__ W4p, const float* __restrict__ b4,
    const float* __restrict__ Wl, const float* __restrict__ bl,
    const float* __restrict__ We, const float* __restrict__ be,
    short* __restrict__ featsb)
{
    __shared__ __align__(16) short In[64 * 40];    // x bf16, rows padded 32->40
    __shared__ __align__(16) short AA[64 * 264];   // act buffer (rows padded 256->264)
    __shared__ __align__(16) short AB[64 * 264];
    const int tid  = threadIdx.x;
    const int lane = tid & 63, wv = tid >> 6;
    const int col  = lane & 15, quad = lane >> 4;
    const int n0   = blockIdx.x * 64;

    // stage image -> In (bf16 of x/255, zero-pad cols 25..31)
    #pragma unroll
    for (int i = 0; i < 8; i++) {
        int idx = tid + i * 256;
        int s = idx >> 5, k = idx & 31;
        float v = (k < 25) ? image[(size_t)(n0 + s) * 25 + k] * (1.0f / 255.0f) : 0.0f;
        In[s * 40 + k] = f2bf(v);
    }

    // loc/energy encoders (independent of MLP): feats cols 32..95
    {
        const int s = tid >> 2, p = tid & 3;         // p: 16-col group
        const float lx = location[(size_t)(n0 + s) * 2 + 0] * 0.1f;
        const float ly = location[(size_t)(n0 + s) * 2 + 1] * 0.1f;
        const float ev = energy[n0 + s] * (1.0f / 200.0f);
        short8 o0, o1;
        #pragma unroll
        for (int jj = 0; jj < 16; jj++) {
            const int cidx = p * 16 + jj;
            float val;
            if (cidx < 32) val = fmaf(lx, Wl[cidx], fmaf(ly, Wl[32 + cidx], bl[cidx]));
            else { const int j2 = cidx - 32; val = fmaf(ev, We[j2], be[j2]); }
            if (jj < 8) o0[jj] = f2bf(val); else o1[jj - 8] = f2bf(val);
        }
        *(short8*)&featsb[(size_t)(n0 + s) * FEAT_ + 32 + p * 16] = o0;
        *(short8*)&featsb[(size_t)(n0 + s) * FEAT_ + 40 + p * 16] = o1;
    }
    __syncthreads();

    // ---- L1: 25(->32) -> 256, wave owns nt {wv, wv+4, wv+8, wv+12}
    {
        short8 aw[4], bx[4];
        #pragma unroll
        for (int i = 0; i < 4; i++) aw[i] = *(const short8*)&W1p[((wv + i * 4) * 64 + lane) * 8];
        #pragma unroll
        for (int st = 0; st < 4; st++) bx[st] = *(const short8*)&In[(st * 16 + col) * 40 + quad * 8];
        f32x4 acc[4][4];
        #pragma unroll
        for (int i = 0; i < 4; i++) {
            const float4 bb = *(const float4*)(b1 + (wv + i * 4) * 16 + quad * 4);
            #pragma unroll
            for (int st = 0; st < 4; st++) acc[i][st] = (f32x4){bb.x, bb.y, bb.z, bb.w};
        }
        #pragma unroll
        for (int i = 0; i < 4; i++)
            #pragma unroll
            for (int st = 0; st < 4; st++)
                acc[i][st] = __builtin_amdgcn_mfma_f32_16x16x32_bf16(aw[i], bx[st], acc[i][st], 0, 0, 0);
        #pragma unroll
        for (int i = 0; i < 4; i++)
            #pragma unroll
            for (int st = 0; st < 4; st++)
                *(short4v*)&AA[(st * 16 + col) * 264 + (wv + i * 4) * 16 + quad * 4] = pack4relu(acc[i][st]);
    }
    __syncthreads();

    // ---- L2: 256 -> 256 : AA -> AB
    {
        f32x4 acc[4][4];
        #pragma unroll
        for (int i = 0; i < 4; i++) {
            const float4 bb = *(const float4*)(b2 + (wv + i * 4) * 16 + quad * 4);
            #pragma unroll
            for (int st = 0; st < 4; st++) acc[i][st] = (f32x4){bb.x, bb.y, bb.z, bb.w};
        }
        for (int kk = 0; kk < 8; kk++) {
            short8 aw[4], bx[4];
            #pragma unroll
            for (int i = 0; i < 4; i++)
                aw[i] = *(const short8*)&W2p[(((wv + i * 4) * 8 + kk) * 64 + lane) * 8];
            #pragma unroll
            for (int st = 0; st < 4; st++)
                bx[st] = *(const short8*)&AA[(st * 16 + col) * 264 + kk * 32 + quad * 8];
            #pragma unroll
            for (int i = 0; i < 4; i++)
                #pragma unroll
                for (int st = 0; st < 4; st++)
                    acc[i][st] = __builtin_amdgcn_mfma_f32_16x16x32_bf16(aw[i], bx[st], acc[i][st], 0, 0, 0);
        }
        #pragma unroll
        for (int i = 0; i < 4; i++)
            #pragma unroll
            for (int st = 0; st < 4; st++)
                *(short4v*)&AB[(st * 16 + col) * 264 + (wv + i * 4) * 16 + quad * 4] = pack4relu(acc[i][st]);
    }
    __syncthreads();

    // ---- L3: 256 -> 128 : AB -> AA (cols 0..127), wave owns nt {wv, wv+4}
    {
        f32x4 acc[2][4];
        #pragma unroll
        for (int i = 0; i < 2; i++) {
            const float4 bb = *(const float4*)(b3 + (wv + i * 4) * 16 + quad * 4);
            #pragma unroll
            for (int st = 0; st < 4; st++) acc[i][st] = (f32x4){bb.x, bb.y, bb.z, bb.w};
        }
        for (int kk = 0; kk < 8; kk++) {
            short8 aw[2], bx[4];
            #pragma unroll
            for (int i = 0; i < 2; i++)
                aw[i] = *(const short8*)&W3p[(((wv + i * 4) * 8 + kk) * 64 + lane) * 8];
            #pragma unroll
            for (int st = 0; st < 4; st++)
                bx[st] = *(const short8*)&AB[(st * 16 + col) * 264 + kk * 32 + quad * 8];
            #pragma unroll
            for (int i = 0; i < 2; i++)
                #pragma unroll
                for (int st = 0; st < 4; st++)
                    acc[i][st] = __builtin_amdgcn_mfma_f32_16x16x32_bf16(aw[i], bx[st], acc[i][st], 0, 0, 0);
        }
        #pragma unroll
        for (int i = 0; i < 2; i++)
            #pragma unroll
            for (int st = 0; st < 4; st++)
                *(short4v*)&AA[(st * 16 + col) * 264 + (wv + i * 4) * 16 + quad * 4] = pack4relu(acc[i][st]);
    }
    __syncthreads();

    // ---- L4: 128 -> 32, wave wv handles sample tile st=wv, nt {0,1}; write feats cols 0..31
    {
        const int st = wv;
        f32x4 acc[2];
        #pragma unroll
        for (int i = 0; i < 2; i++) {
            const float4 bb = *(const float4*)(b4 + i * 16 + quad * 4);
            acc[i] = (f32x4){bb.x, bb.y, bb.z, bb.w};
        }
        for (int kk = 0; kk < 4; kk++) {
            const short8 bx = *(const short8*)&AA[(st * 16 + col) * 264 + kk * 32 + quad * 8];
            #pragma unroll
            for (int i = 0; i < 2; i++) {
                const short8 aw = *(const short8*)&W4p[((i * 4 + kk) * 64 + lane) * 8];
                acc[i] = __builtin_amdgcn_mfma_f32_16x16x32_bf16(aw, bx, acc[i], 0, 0, 0);
            }
        }
        #pragma unroll
        for (int i = 0; i < 2; i++)
            *(short4v*)&featsb[(size_t)(n0 + st * 16 + col) * FEAT_ + i * 16 + quad * 4] = pack4relu(acc[i]);
    }
}

// ---------------- MFMA LSTM (unchanged except bf16 feats staging) ----------------
__global__ __launch_bounds__(512) void lstm_kernel(
    const short* __restrict__ featsb, const int* __restrict__ done,
    const float* __restrict__ h0, const float* __restrict__ c0,
    const short* __restrict__ Wtp, const float* __restrict__ bias,
    const float* __restrict__ Wa, const float* __restrict__ ba,
    const float* __restrict__ Wc, const float* __restrict__ bc,
    float* __restrict__ out)
{
#define AROW 232
#define HROW 136
    __shared__ __align__(16) short A[16 * AROW];
    __shared__ __align__(16) short Hout[16 * HROW];
    __shared__ __align__(16) short HW[4 * 64 * 8];
    __shared__ __align__(16) short WL[112 * 64 * 8];
    __shared__ __align__(16) short WL2[16 * 64 * 8];

    const int tid = threadIdx.x;
    const int r0 = blockIdx.x * 16;
    const int lane = tid & 63;
    const int wv = tid >> 6;
    const int col = lane & 15;
    const int quad = lane >> 4;
    const int u = (wv << 4) + col;

    {
        const float4* src = (const float4*)Wtp;
        float4* dst = (float4*)WL;
        for (int i = tid; i < 112 * 64; i += 512) dst[i] = src[i];
        float4* dst2 = (float4*)WL2;
        for (int i = tid; i < 16 * 64; i += 512) {
            int fid = (16 + (i >> 6)) * 7;
            dst2[i] = src[fid * 64 + (i & 63)];
        }
    }
    for (int idx = tid; idx < 4 * 64 * 8; idx += 512) {
        int j = idx & 7, L = (idx >> 3) & 63, kk2 = idx >> 9;
        int k = kk2 * 32 + ((L >> 4) << 3) + j;
        int n = L & 15;
        float v = (n < 6) ? Wa[k * 6 + n] : (n == 6 ? Wc[k] : 0.0f);
        HW[idx] = f2bf(v);
    }
    f32x4 c;
    #pragma unroll
    for (int r = 0; r < 4; r++) {
        int s = (quad << 2) + r;
        float m = 1.0f - (float)done[r0 + s];
        c[r] = c0[(size_t)(r0 + s) * H_ + u] * m;
        float h = h0[(size_t)(r0 + s) * H_ + u] * m;
        A[s * AROW + 96 + u] = f2bf(h);
    }
    if (tid < 192) {
        int s = tid / 12, gp = tid % 12;
        *(short8*)&A[s * AROW + gp * 8] =
            *(const short8*)&featsb[(size_t)(r0 + s) * FEAT_ + gp * 8];
    }
    const float bi0 = bias[((wv +  0) << 4) + col];
    const float bi1 = bias[((wv +  8) << 4) + col];
    const float bi2 = bias[((wv + 16) << 4) + col];
    const float bi3 = bias[((wv + 24) << 4) + col];
    const float hb = (col < 6) ? ba[col] : (col == 6 ? bc[0] : 0.0f);
    __syncthreads();

    for (int t = 0; t < T_; t++) {
        f32x4 acc0 = {bi0, bi0, bi0, bi0};
        f32x4 acc1 = {bi1, bi1, bi1, bi1};
        f32x4 acc2 = {bi2, bi2, bi2, bi2};
        f32x4 acc3 = {bi3, bi3, bi3, bi3};
        #pragma unroll
        for (int kk = 0; kk < 7; kk++) {
            const short8 af = *(const short8*)&A[col * AROW + kk * 32 + (quad << 3)];
            const short8 b0 = *(const short8*)&WL[(((wv + 0) * 7 + kk) * 64 + lane) * 8];
            const short8 b1 = *(const short8*)&WL[(((wv + 8) * 7 + kk) * 64 + lane) * 8];
            const short8 b2 = (kk == 0)
                ? *(const short8*)&WL2[(((wv + 0)) * 64 + lane) * 8]
                : *(const short8*)&Wtp[(size_t)((((wv + 16) * 7 + kk) * 64 + lane)) * 8];
            const short8 b3 = (kk == 0)
                ? *(const short8*)&WL2[(((wv + 8)) * 64 + lane) * 8]
                : *(const short8*)&Wtp[(size_t)((((wv + 24) * 7 + kk) * 64 + lane)) * 8];
            acc0 = __builtin_amdgcn_mfma_f32_16x16x32_bf16(af, b0, acc0, 0, 0, 0);
            acc1 = __builtin_amdgcn_mfma_f32_16x16x32_bf16(af, b1, acc1, 0, 0, 0);
            acc2 = __builtin_amdgcn_mfma_f32_16x16x32_bf16(af, b2, acc2, 0, 0, 0);
            acc3 = __builtin_amdgcn_mfma_f32_16x16x32_bf16(af, b3, acc3, 0, 0, 0);
        }
        f32x4 hm, hu;
        #pragma unroll
        for (int r = 0; r < 4; r++) {
            float ig = fsig(acc0[r]);
            float fg = fsig(acc1[r]);
            float gg = ftanh(acc2[r]);
            float og = fsig(acc3[r]);
            float cn = fmaf(fg, c[r], ig * gg);
            float h = og * ftanh(cn);
            float m = 1.0f;
            if (t < T_ - 1) m = 1.0f - (float)done[(size_t)(t + 1) * B_ + r0 + (quad << 2) + r];
            c[r] = cn * m;
            hm[r] = h * m;
            hu[r] = h;
        }
        __syncthreads();
        #pragma unroll
        for (int r = 0; r < 4; r++) {
            int s = (quad << 2) + r;
            A[s * AROW + 96 + u] = f2bf(hm[r]);
            Hout[s * HROW + u] = f2bf(hu[r]);
        }
        if (wv != 0 && t < T_ - 1) {
            int w2 = tid - 64;
            if (w2 < 192) {
                int s = w2 / 12, gp = w2 % 12;
                *(short8*)&A[s * AROW + gp * 8] =
                    *(const short8*)&featsb[((size_t)(t + 1) * B_ + r0 + s) * FEAT_ + gp * 8];
            }
        }
        __syncthreads();
        if (wv == 0) {
            f32x4 ha = {hb, hb, hb, hb};
            #pragma unroll
            for (int kk2 = 0; kk2 < 4; kk2++) {
                const short8 hf = *(const short8*)&Hout[col * HROW + kk2 * 32 + (quad << 3)];
                const short8 wf = *(const short8*)&HW[(kk2 * 64 + lane) * 8];
                ha = __builtin_amdgcn_mfma_f32_16x16x32_bf16(hf, wf, ha, 0, 0, 0);
            }
            if (col < 7) {
                #pragma unroll
                for (int r = 0; r < 4; r++) {
                    int s = (quad << 2) + r;
                    out[((size_t)t * B_ + r0 + s) * 7 + col] = ha[r];
                }
            }
        }
    }
#undef AROW
#undef HROW
}

extern "C" void kernel_launch(void* const* d_in, const int* in_sizes, int n_in,
                              void* d_out, int out_size, void* d_ws, size_t ws_size,
                              hipStream_t stream) {
    const float* image    = (const float*)d_in[0];
    const float* location = (const float*)d_in[1];
    const float* energy   = (const float*)d_in[2];
    const int*   done     = (const int*)d_in[3];
    const float* h0       = (const float*)d_in[4];
    const float* c0       = (const float*)d_in[5];
    const float* W1 = (const float*)d_in[6];   const float* b1 = (const float*)d_in[7];
    const float* W2 = (const float*)d_in[8];   const float* b2 = (const float*)d_in[9];
    const float* W3 = (const float*)d_in[10];  const float* b3 = (const float*)d_in[11];
    const float* W4 = (const float*)d_in[12];  const float* b4 = (const float*)d_in[13];
    const float* Wl = (const float*)d_in[14];  const float* bl = (const float*)d_in[15];
    const float* We = (const float*)d_in[16];  const float* be = (const float*)d_in[17];
    const float* Wih = (const float*)d_in[18]; const float* Whh = (const float*)d_in[19];
    const float* bih = (const float*)d_in[20]; const float* bhh = (const float*)d_in[21];
    const float* Wa = (const float*)d_in[22];  const float* ba = (const float*)d_in[23];
    const float* Wc = (const float*)d_in[24];  const float* bc = (const float*)d_in[25];

    char* ws = (char*)d_ws;
    short* Wtp   = (short*)ws;                     // 229376 B
    float* bias  = (float*)(ws + 229376);          // 2048 B
    short* W1p   = (short*)(ws + 231424);          // 16384 B
    short* W2p   = (short*)(ws + 247808);          // 131072 B
    short* W3p   = (short*)(ws + 378880);          // 65536 B
    short* W4p   = (short*)(ws + 444416);          // 8192 B
    short* featsb = (short*)(ws + 452608);         // N*96 bf16 = 100663296 B
    float* out   = (float*)d_out;

    prep_kernel<<<882, 256, 0, stream>>>(Wih, Whh, bih, bhh, W1, W2, W3, W4,
                                         Wtp, bias, W1p, W2p, W3p, W4p);
    enc_kernel<<<N_ / 64, 256, 0, stream>>>(image, location, energy,
                                            W1p, b1, W2p, b2, W3p, b3, W4p, b4,
                                            Wl, bl, We, be, featsb);
    lstm_kernel<<<B_ / 16, 512, 0, stream>>>(featsb, done, h0, c0, Wtp, bias,
                                             Wa, ba, Wc, bc, out);
}

// Round 4
// 572.675 us; speedup vs baseline: 6.9667x; 1.0222x over previous
//
#include <hip/hip_runtime.h>

#define T_ 128
#define B_ 4096
#define N_ (T_*B_)
#define H_ 128
#define FEAT_ 96
#define K_ 224
#define G4H_ 512

typedef __attribute__((ext_vector_type(8))) short short8;   // 8 bf16 = 4 VGPRs
typedef __attribute__((ext_vector_type(4))) short short4v;  // 4 bf16 = 2 VGPRs
typedef __attribute__((ext_vector_type(4))) float f32x4;

__device__ __forceinline__ float fsig(float x) {
    float e = __builtin_amdgcn_exp2f(-1.44269504088896340736f * x);
    return __builtin_amdgcn_rcpf(1.0f + e);
}
__device__ __forceinline__ float ftanh(float x) {
    float e = __builtin_amdgcn_exp2f(-2.88539008177792681472f * x);
    return fmaf(2.0f, __builtin_amdgcn_rcpf(1.0f + e), -1.0f);
}
__device__ __forceinline__ short f2bf(float f) {
    unsigned u = __builtin_bit_cast(unsigned, f);
    u += 0x7fff + ((u >> 16) & 1);              // RNE
    return (short)(u >> 16);
}
__device__ __forceinline__ short4v pack4relu(const f32x4 a) {
    short4v v;
    v[0] = f2bf(fmaxf(a[0], 0.f)); v[1] = f2bf(fmaxf(a[1], 0.f));
    v[2] = f2bf(fmaxf(a[2], 0.f)); v[3] = f2bf(fmaxf(a[3], 0.f));
    return v;
}

// ---------------- prep: pack all weights into bf16 MFMA-fragment order ----------------
__global__ __launch_bounds__(256) void prep_kernel(
    const float* __restrict__ Wih, const float* __restrict__ Whh,
    const float* __restrict__ bih, const float* __restrict__ bhh,
    const float* __restrict__ W1, const float* __restrict__ W2,
    const float* __restrict__ W3, const float* __restrict__ W4,
    short* __restrict__ Wtp, float* __restrict__ bias,
    short* __restrict__ W1p, short* __restrict__ W2p,
    short* __restrict__ W3p, short* __restrict__ W4p)
{
    int idx = blockIdx.x * 256 + threadIdx.x;
    if (idx < 114688) {                     // LSTM combined [224][512]
        int j = idx & 7, L = (idx >> 3) & 63, r = idx >> 9;
        int kk = r % 7, n = r / 7;
        int k = kk * 32 + ((L >> 4) << 3) + j;
        int g = (n << 4) + (L & 15);
        float v = (k < FEAT_) ? Wih[g * FEAT_ + k] : Whh[g * H_ + (k - FEAT_)];
        Wtp[idx] = f2bf(v);
        return;
    }
    int e = idx - 114688;
    if (e < 8192) {                         // W1 [25,256], zero-pad k>=25
        int j = e & 7, L = (e >> 3) & 63, nt = e >> 9;
        int k = ((L >> 4) << 3) + j;
        int o = nt * 16 + (L & 15);
        W1p[e] = (k < 25) ? f2bf(W1[k * 256 + o]) : (short)0;
        return;
    }
    e -= 8192;
    if (e < 65536) {                        // W2 [256,256]
        int j = e & 7, L = (e >> 3) & 63, f = e >> 9;
        int kk = f & 7, nt = f >> 3;
        int k = kk * 32 + ((L >> 4) << 3) + j;
        W2p[e] = f2bf(W2[k * 256 + nt * 16 + (L & 15)]);
        return;
    }
    e -= 65536;
    if (e < 32768) {                        // W3 [256,128]
        int j = e & 7, L = (e >> 3) & 63, f = e >> 9;
        int kk = f & 7, nt = f >> 3;
        int k = kk * 32 + ((L >> 4) << 3) + j;
        W3p[e] = f2bf(W3[k * 128 + nt * 16 + (L & 15)]);
        return;
    }
    e -= 32768;
    if (e < 4096) {                         // W4 [128,32]
        int j = e & 7, L = (e >> 3) & 63, f = e >> 9;
        int kk = f & 3, nt = f >> 2;
        int k = kk * 32 + ((L >> 4) << 3) + j;
        W4p[e] = f2bf(W4[k * 32 + nt * 16 + (L & 15)]);
        return;
    }
    e -= 4096;
    if (e < 512) bias[e] = bih[e] + bhh[e];
}

// ---------------- MFMA encoder: 32 samples/block, 256 thr (4 waves), 4 blocks/CU ------
__global__ __launch_bounds__(256) void enc_kernel(
    const float* __restrict__ image, const float* __restrict__ location,
    const float* __restrict__ energy,
    const short* __restrict__ W1p, const float* __restrict__ b1,
    const short* __restrict__ W2p, const float* __restrict__ b2,
    const short* __restrict__ W3p, const float* __restrict__ b3,
    const short* __restrict__ W4p, const float* __restrict__ b4,
    const float* __restrict__ Wl, const float* __restrict__ bl,
    const float* __restrict__ We, const float* __restrict__ be,
    short* __restrict__ featsb)
{
    __shared__ __align__(16) short In[32 * 40];    // x bf16, rows padded 32->40
    __shared__ __align__(16) short AA[32 * 264];   // act buffers (rows padded 256->264)
    __shared__ __align__(16) short AB[32 * 264];
    const int tid  = threadIdx.x;
    const int lane = tid & 63, wv = tid >> 6;
    const int col  = lane & 15, quad = lane >> 4;
    const int n0   = blockIdx.x * 32;

    // stage image -> In (bf16 of x/255, zero-pad cols 25..31)
    #pragma unroll
    for (int i = 0; i < 4; i++) {
        int idx = tid + i * 256;
        int s = idx >> 5, k = idx & 31;
        float v = (k < 25) ? image[(size_t)(n0 + s) * 25 + k] * (1.0f / 255.0f) : 0.0f;
        In[s * 40 + k] = f2bf(v);
    }

    // loc/energy encoders: feats cols 32..95 (32 samples x 4 col-groups = 128 threads)
    if (tid < 128) {
        const int s = tid >> 2, p = tid & 3;
        const float lx = location[(size_t)(n0 + s) * 2 + 0] * 0.1f;
        const float ly = location[(size_t)(n0 + s) * 2 + 1] * 0.1f;
        const float ev = energy[n0 + s] * (1.0f / 200.0f);
        short8 o0, o1;
        #pragma unroll
        for (int jj = 0; jj < 16; jj++) {
            const int cidx = p * 16 + jj;
            float val;
            if (cidx < 32) val = fmaf(lx, Wl[cidx], fmaf(ly, Wl[32 + cidx], bl[cidx]));
            else { const int j2 = cidx - 32; val = fmaf(ev, We[j2], be[j2]); }
            if (jj < 8) o0[jj] = f2bf(val); else o1[jj - 8] = f2bf(val);
        }
        *(short8*)&featsb[(size_t)(n0 + s) * FEAT_ + 32 + p * 16] = o0;
        *(short8*)&featsb[(size_t)(n0 + s) * FEAT_ + 40 + p * 16] = o1;
    }
    __syncthreads();

    // ---- L1: 25(->32) -> 256, wave owns nt {wv, wv+4, wv+8, wv+12}, st 0..1
    {
        short8 aw[4], bx[2];
        #pragma unroll
        for (int i = 0; i < 4; i++) aw[i] = *(const short8*)&W1p[((wv + i * 4) * 64 + lane) * 8];
        #pragma unroll
        for (int st = 0; st < 2; st++) bx[st] = *(const short8*)&In[(st * 16 + col) * 40 + quad * 8];
        f32x4 acc[4][2];
        #pragma unroll
        for (int i = 0; i < 4; i++) {
            const float4 bb = *(const float4*)(b1 + (wv + i * 4) * 16 + quad * 4);
            #pragma unroll
            for (int st = 0; st < 2; st++) acc[i][st] = (f32x4){bb.x, bb.y, bb.z, bb.w};
        }
        #pragma unroll
        for (int i = 0; i < 4; i++)
            #pragma unroll
            for (int st = 0; st < 2; st++)
                acc[i][st] = __builtin_amdgcn_mfma_f32_16x16x32_bf16(aw[i], bx[st], acc[i][st], 0, 0, 0);
        #pragma unroll
        for (int i = 0; i < 4; i++)
            #pragma unroll
            for (int st = 0; st < 2; st++)
                *(short4v*)&AA[(st * 16 + col) * 264 + (wv + i * 4) * 16 + quad * 4] = pack4relu(acc[i][st]);
    }
    __syncthreads();

    // ---- L2: 256 -> 256 : AA -> AB (kk loop with weight prefetch)
    {
        f32x4 acc[4][2];
        #pragma unroll
        for (int i = 0; i < 4; i++) {
            const float4 bb = *(const float4*)(b2 + (wv + i * 4) * 16 + quad * 4);
            #pragma unroll
            for (int st = 0; st < 2; st++) acc[i][st] = (f32x4){bb.x, bb.y, bb.z, bb.w};
        }
        short8 awc[4];
        #pragma unroll
        for (int i = 0; i < 4; i++)
            awc[i] = *(const short8*)&W2p[(((wv + i * 4) * 8 + 0) * 64 + lane) * 8];
        #pragma unroll
        for (int kk = 0; kk < 8; kk++) {
            short8 awn[4];
            if (kk < 7) {
                #pragma unroll
                for (int i = 0; i < 4; i++)
                    awn[i] = *(const short8*)&W2p[(((wv + i * 4) * 8 + kk + 1) * 64 + lane) * 8];
            }
            short8 bx[2];
            #pragma unroll
            for (int st = 0; st < 2; st++)
                bx[st] = *(const short8*)&AA[(st * 16 + col) * 264 + kk * 32 + quad * 8];
            #pragma unroll
            for (int i = 0; i < 4; i++)
                #pragma unroll
                for (int st = 0; st < 2; st++)
                    acc[i][st] = __builtin_amdgcn_mfma_f32_16x16x32_bf16(awc[i], bx[st], acc[i][st], 0, 0, 0);
            if (kk < 7) {
                #pragma unroll
                for (int i = 0; i < 4; i++) awc[i] = awn[i];
            }
        }
        #pragma unroll
        for (int i = 0; i < 4; i++)
            #pragma unroll
            for (int st = 0; st < 2; st++)
                *(short4v*)&AB[(st * 16 + col) * 264 + (wv + i * 4) * 16 + quad * 4] = pack4relu(acc[i][st]);
    }
    __syncthreads();

    // ---- L3: 256 -> 128 : AB -> AA, wave owns nt {wv, wv+4}
    {
        f32x4 acc[2][2];
        #pragma unroll
        for (int i = 0; i < 2; i++) {
            const float4 bb = *(const float4*)(b3 + (wv + i * 4) * 16 + quad * 4);
            #pragma unroll
            for (int st = 0; st < 2; st++) acc[i][st] = (f32x4){bb.x, bb.y, bb.z, bb.w};
        }
        short8 awc[2];
        #pragma unroll
        for (int i = 0; i < 2; i++)
            awc[i] = *(const short8*)&W3p[(((wv + i * 4) * 8 + 0) * 64 + lane) * 8];
        #pragma unroll
        for (int kk = 0; kk < 8; kk++) {
            short8 awn[2];
            if (kk < 7) {
                #pragma unroll
                for (int i = 0; i < 2; i++)
                    awn[i] = *(const short8*)&W3p[(((wv + i * 4) * 8 + kk + 1) * 64 + lane) * 8];
            }
            short8 bx[2];
            #pragma unroll
            for (int st = 0; st < 2; st++)
                bx[st] = *(const short8*)&AB[(st * 16 + col) * 264 + kk * 32 + quad * 8];
            #pragma unroll
            for (int i = 0; i < 2; i++)
                #pragma unroll
                for (int st = 0; st < 2; st++)
                    acc[i][st] = __builtin_amdgcn_mfma_f32_16x16x32_bf16(awc[i], bx[st], acc[i][st], 0, 0, 0);
            if (kk < 7) {
                #pragma unroll
                for (int i = 0; i < 2; i++) awc[i] = awn[i];
            }
        }
        #pragma unroll
        for (int i = 0; i < 2; i++)
            #pragma unroll
            for (int st = 0; st < 2; st++)
                *(short4v*)&AA[(st * 16 + col) * 264 + (wv + i * 4) * 16 + quad * 4] = pack4relu(acc[i][st]);
    }
    __syncthreads();

    // ---- L4: 128 -> 32, waves 0..1 (st = wv), nt {0,1}; write feats cols 0..31
    if (wv < 2) {
        const int st = wv;
        f32x4 acc[2];
        #pragma unroll
        for (int i = 0; i < 2; i++) {
            const float4 bb = *(const float4*)(b4 + i * 16 + quad * 4);
            acc[i] = (f32x4){bb.x, bb.y, bb.z, bb.w};
        }
        #pragma unroll
        for (int kk = 0; kk < 4; kk++) {
            const short8 bx = *(const short8*)&AA[(st * 16 + col) * 264 + kk * 32 + quad * 8];
            #pragma unroll
            for (int i = 0; i < 2; i++) {
                const short8 aw = *(const short8*)&W4p[((i * 4 + kk) * 64 + lane) * 8];
                acc[i] = __builtin_amdgcn_mfma_f32_16x16x32_bf16(aw, bx, acc[i], 0, 0, 0);
            }
        }
        #pragma unroll
        for (int i = 0; i < 2; i++)
            *(short4v*)&featsb[(size_t)(n0 + st * 16 + col) * FEAT_ + i * 16 + quad * 4] = pack4relu(acc[i]);
    }
}

// ---------------- MFMA LSTM v2: 1 barrier/step, double-buffered A, reg-prefetched x,
// done-masks in LDS, h stored unmasked (mask applied at A-fragment read; exact 0/1) ----
__global__ __launch_bounds__(512) void lstm_kernel(
    const short* __restrict__ featsb, const int* __restrict__ done,
    const float* __restrict__ h0, const float* __restrict__ c0,
    const short* __restrict__ Wtp, const float* __restrict__ bias,
    const float* __restrict__ Wa, const float* __restrict__ ba,
    const float* __restrict__ Wc, const float* __restrict__ bc,
    float* __restrict__ out)
{
#define AROW 232
    __shared__ __align__(16) short A[2][16 * AROW];      // [buf][s][0:96 x | 96:224 h]
    __shared__ __align__(16) short HW[4 * 64 * 8];       // head B-frags (4 KB)
    __shared__ __align__(16) short WL[112 * 64 * 8];     // held frags n<16 (112 KB)
    __shared__ __align__(16) short WL2[16 * 64 * 8];     // held frags n>=16, kk==0 (16 KB)
    __shared__ float Ml[T_ * 16];                        // reset masks 1-done (8 KB)

    const int tid = threadIdx.x;
    const int r0 = blockIdx.x * 16;
    const int lane = tid & 63;
    const int wv = tid >> 6;
    const int col = lane & 15;
    const int quad = lane >> 4;
    const int u = (wv << 4) + col;

    // held weight frags -> LDS
    {
        const float4* src = (const float4*)Wtp;
        float4* dst = (float4*)WL;
        for (int i = tid; i < 112 * 64; i += 512) dst[i] = src[i];
        float4* dst2 = (float4*)WL2;
        for (int i = tid; i < 16 * 64; i += 512) {
            int fid = (16 + (i >> 6)) * 7;
            dst2[i] = src[fid * 64 + (i & 63)];
        }
    }
    // head weight B-frags
    for (int idx = tid; idx < 4 * 64 * 8; idx += 512) {
        int j = idx & 7, L = (idx >> 3) & 63, kk2 = idx >> 9;
        int k = kk2 * 32 + ((L >> 4) << 3) + j;
        int n = L & 15;
        float v = (n < 6) ? Wa[k * 6 + n] : (n == 6 ? Wc[k] : 0.0f);
        HW[idx] = f2bf(v);
    }
    // reset masks for all T steps (coalesced 16-dword rows)
    for (int idx = tid; idx < T_ * 16; idx += 512)
        Ml[idx] = 1.0f - (float)done[(size_t)(idx >> 4) * B_ + r0 + (idx & 15)];

    // init state: c masked by done[0]; h0 stored UNMASKED (masked at read via Ml[0])
    f32x4 c;
    #pragma unroll
    for (int r = 0; r < 4; r++) {
        int s = (quad << 2) + r;
        float m = 1.0f - (float)done[r0 + s];
        c[r] = c0[(size_t)(r0 + s) * H_ + u] * m;
        A[0][s * AROW + 96 + u] = f2bf(h0[(size_t)(r0 + s) * H_ + u]);
    }
    // stage x_0 into A[0]
    if (tid < 192) {
        int s = tid / 12, gp = tid % 12;
        *(short8*)&A[0][s * AROW + gp * 8] =
            *(const short8*)&featsb[(size_t)(r0 + s) * FEAT_ + gp * 8];
    }
    const float bi0 = bias[((wv +  0) << 4) + col];
    const float bi1 = bias[((wv +  8) << 4) + col];
    const float bi2 = bias[((wv + 16) << 4) + col];
    const float bi3 = bias[((wv + 24) << 4) + col];
    const float hb = (col < 6) ? ba[col] : (col == 6 ? bc[0] : 0.0f);
    const int w2 = tid - 64;                       // staging lanes: waves 1..3
    const bool stager = (w2 >= 0) && (w2 < 192);
    const int ss = stager ? (w2 / 12) : 0;
    const int gp = stager ? (w2 % 12) : 0;
    __syncthreads();

    for (int t = 0; t < T_; t++) {
        const int cur = t & 1, nxt = cur ^ 1;
        // prefetch x_{t+1} into registers (latency hidden by GEMM)
        short8 xreg;
        if (stager && t < T_ - 1)
            xreg = *(const short8*)&featsb[((size_t)(t + 1) * B_ + r0 + ss) * FEAT_ + gp * 8];

        // GEMM: gates = [x_t | m*h] @ Wt + bias   (mask h-frags per-lane, m in {0,1})
        const float mcol = Ml[t * 16 + col];
        f32x4 acc0 = {bi0, bi0, bi0, bi0};
        f32x4 acc1 = {bi1, bi1, bi1, bi1};
        f32x4 acc2 = {bi2, bi2, bi2, bi2};
        f32x4 acc3 = {bi3, bi3, bi3, bi3};
        #pragma unroll
        for (int kk = 0; kk < 7; kk++) {
            short8 af = *(const short8*)&A[cur][col * AROW + kk * 32 + (quad << 3)];
            if (kk >= 3 && mcol == 0.0f) af = (short8){0,0,0,0,0,0,0,0};
            const short8 b0 = *(const short8*)&WL[(((wv + 0) * 7 + kk) * 64 + lane) * 8];
            const short8 b1 = *(const short8*)&WL[(((wv + 8) * 7 + kk) * 64 + lane) * 8];
            const short8 b2 = (kk == 0)
                ? *(const short8*)&WL2[(((wv + 0)) * 64 + lane) * 8]
                : *(const short8*)&Wtp[(size_t)((((wv + 16) * 7 + kk) * 64 + lane)) * 8];
            const short8 b3 = (kk == 0)
                ? *(const short8*)&WL2[(((wv + 8)) * 64 + lane) * 8]
                : *(const short8*)&Wtp[(size_t)((((wv + 24) * 7 + kk) * 64 + lane)) * 8];
            acc0 = __builtin_amdgcn_mfma_f32_16x16x32_bf16(af, b0, acc0, 0, 0, 0);
            acc1 = __builtin_amdgcn_mfma_f32_16x16x32_bf16(af, b1, acc1, 0, 0, 0);
            acc2 = __builtin_amdgcn_mfma_f32_16x16x32_bf16(af, b2, acc2, 0, 0, 0);
            acc3 = __builtin_amdgcn_mfma_f32_16x16x32_bf16(af, b3, acc3, 0, 0, 0);
        }

        // cell update; pre-mask c with m[t+1]; h stored UNMASKED
        float4 mn = {1.f, 1.f, 1.f, 1.f};
        if (t < T_ - 1) mn = *(const float4*)&Ml[(t + 1) * 16 + (quad << 2)];
        #pragma unroll
        for (int r = 0; r < 4; r++) {
            float ig = fsig(acc0[r]);
            float fg = fsig(acc1[r]);
            float gg = ftanh(acc2[r]);
            float og = fsig(acc3[r]);
            float cn = fmaf(fg, c[r], ig * gg);
            float h = og * ftanh(cn);
            c[r] = cn * ((&mn.x)[r]);
            A[nxt][((quad << 2) + r) * AROW + 96 + u] = f2bf(h);
        }
        // staging waves write x_{t+1} to A[nxt]
        if (stager && t < T_ - 1)
            *(short8*)&A[nxt][ss * AROW + gp * 8] = xreg;
        __syncthreads();

        // wave 0: heads for step t from A[nxt] h-region (unmasked h_t)
        if (wv == 0) {
            f32x4 ha = {hb, hb, hb, hb};
            #pragma unroll
            for (int kk2 = 0; kk2 < 4; kk2++) {
                const short8 hf = *(const short8*)&A[nxt][col * AROW + 96 + kk2 * 32 + (quad << 3)];
                const short8 wf = *(const short8*)&HW[(kk2 * 64 + lane) * 8];
                ha = __builtin_amdgcn_mfma_f32_16x16x32_bf16(hf, wf, ha, 0, 0, 0);
            }
            if (col < 7) {
                #pragma unroll
                for (int r = 0; r < 4; r++) {
                    int s = (quad << 2) + r;
                    out[((size_t)t * B_ + r0 + s) * 7 + col] = ha[r];
                }
            }
        }
    }
#undef AROW
}

extern "C" void kernel_launch(void* const* d_in, const int* in_sizes, int n_in,
                              void* d_out, int out_size, void* d_ws, size_t ws_size,
                              hipStream_t stream) {
    const float* image    = (const float*)d_in[0];
    const float* location = (const float*)d_in[1];
    const float* energy   = (const float*)d_in[2];
    const int*   done     = (const int*)d_in[3];
    const float* h0       = (const float*)d_in[4];
    const float* c0       = (const float*)d_in[5];
    const float* W1 = (const float*)d_in[6];   const float* b1 = (const float*)d_in[7];
    const float* W2 = (const float*)d_in[8];   const float* b2 = (const float*)d_in[9];
    const float* W3 = (const float*)d_in[10];  const float* b3 = (const float*)d_in[11];
    const float* W4 = (const float*)d_in[12];  const float* b4 = (const float*)d_in[13];
    const float* Wl = (const float*)d_in[14];  const float* bl = (const float*)d_in[15];
    const float* We = (const float*)d_in[16];  const float* be = (const float*)d_in[17];
    const float* Wih = (const float*)d_in[18]; const float* Whh = (const float*)d_in[19];
    const float* bih = (const float*)d_in[20]; const float* bhh = (const float*)d_in[21];
    const float* Wa = (const float*)d_in[22];  const float* ba = (const float*)d_in[23];
    const float* Wc = (const float*)d_in[24];  const float* bc = (const float*)d_in[25];

    char* ws = (char*)d_ws;
    short* Wtp   = (short*)ws;                     // 229376 B
    float* bias  = (float*)(ws + 229376);          // 2048 B
    short* W1p   = (short*)(ws + 231424);          // 16384 B
    short* W2p   = (short*)(ws + 247808);          // 131072 B
    short* W3p   = (short*)(ws + 378880);          // 65536 B
    short* W4p   = (short*)(ws + 444416);          // 8192 B
    short* featsb = (short*)(ws + 452608);         // N*96 bf16 = 100663296 B
    float* out   = (float*)d_out;

    prep_kernel<<<882, 256, 0, stream>>>(Wih, Whh, bih, bhh, W1, W2, W3, W4,
                                         Wtp, bias, W1p, W2p, W3p, W4p);
    enc_kernel<<<N_ / 32, 256, 0, stream>>>(image, location, energy,
                                            W1p, b1, W2p, b2, W3p, b3, W4p, b4,
                                            Wl, bl, We, be, featsb);
    lstm_kernel<<<B_ / 16, 512, 0, stream>>>(featsb, done, h0, c0, Wtp, bias,
                                             Wa, ba, Wc, bc, out);
}

// Round 5
// 445.467 us; speedup vs baseline: 8.9561x; 1.2856x over previous
//
#include <hip/hip_runtime.h>

#define T_ 128
#define B_ 4096
#define N_ (T_*B_)
#define H_ 128
#define FEAT_ 96
#define K_ 224
#define G4H_ 512

typedef __attribute__((ext_vector_type(8))) short short8;   // 8 bf16 = 4 VGPRs
typedef __attribute__((ext_vector_type(4))) short short4v;  // 4 bf16 = 2 VGPRs
typedef __attribute__((ext_vector_type(4))) float f32x4;

__device__ __forceinline__ float fsig(float x) {
    float e = __builtin_amdgcn_exp2f(-1.44269504088896340736f * x);
    return __builtin_amdgcn_rcpf(1.0f + e);
}
__device__ __forceinline__ float ftanh(float x) {
    float e = __builtin_amdgcn_exp2f(-2.88539008177792681472f * x);
    return fmaf(2.0f, __builtin_amdgcn_rcpf(1.0f + e), -1.0f);
}
__device__ __forceinline__ short f2bf(float f) {
    unsigned u = __builtin_bit_cast(unsigned, f);
    u += 0x7fff + ((u >> 16) & 1);              // RNE
    return (short)(u >> 16);
}
__device__ __forceinline__ short4v pack4relu(const f32x4 a) {
    short4v v;
    v[0] = f2bf(fmaxf(a[0], 0.f)); v[1] = f2bf(fmaxf(a[1], 0.f));
    v[2] = f2bf(fmaxf(a[2], 0.f)); v[3] = f2bf(fmaxf(a[3], 0.f));
    return v;
}

// feats stored in MFMA-fragment order per 16-sample group:
// featsb[ ((t*256 + b/16)*3 + kk)*512 + L*8 + j ] = feats[t][b] element
//   k = kk*32 + (L>>4)*8 + j (feature), sample-in-group = L&15.
#define FBASE(t, grp, kk) ((((size_t)(t) * 256 + (grp)) * 3 + (kk)) * 512)

// ---------------- prep: pack all weights into bf16 MFMA-fragment order ----------------
__global__ __launch_bounds__(256) void prep_kernel(
    const float* __restrict__ Wih, const float* __restrict__ Whh,
    const float* __restrict__ bih, const float* __restrict__ bhh,
    const float* __restrict__ W1, const float* __restrict__ W2,
    const float* __restrict__ W3, const float* __restrict__ W4,
    short* __restrict__ Wtp, float* __restrict__ bias,
    short* __restrict__ W1p, short* __restrict__ W2p,
    short* __restrict__ W3p, short* __restrict__ W4p)
{
    int idx = blockIdx.x * 256 + threadIdx.x;
    if (idx < 114688) {                     // LSTM combined [224][512]
        int j = idx & 7, L = (idx >> 3) & 63, r = idx >> 9;
        int kk = r % 7, n = r / 7;
        int k = kk * 32 + ((L >> 4) << 3) + j;
        int g = (n << 4) + (L & 15);
        float v = (k < FEAT_) ? Wih[g * FEAT_ + k] : Whh[g * H_ + (k - FEAT_)];
        Wtp[idx] = f2bf(v);
        return;
    }
    int e = idx - 114688;
    if (e < 8192) {                         // W1 [25,256], zero-pad k>=25
        int j = e & 7, L = (e >> 3) & 63, nt = e >> 9;
        int k = ((L >> 4) << 3) + j;
        int o = nt * 16 + (L & 15);
        W1p[e] = (k < 25) ? f2bf(W1[k * 256 + o]) : (short)0;
        return;
    }
    e -= 8192;
    if (e < 65536) {                        // W2 [256,256]
        int j = e & 7, L = (e >> 3) & 63, f = e >> 9;
        int kk = f & 7, nt = f >> 3;
        int k = kk * 32 + ((L >> 4) << 3) + j;
        W2p[e] = f2bf(W2[k * 256 + nt * 16 + (L & 15)]);
        return;
    }
    e -= 65536;
    if (e < 32768) {                        // W3 [256,128]
        int j = e & 7, L = (e >> 3) & 63, f = e >> 9;
        int kk = f & 7, nt = f >> 3;
        int k = kk * 32 + ((L >> 4) << 3) + j;
        W3p[e] = f2bf(W3[k * 128 + nt * 16 + (L & 15)]);
        return;
    }
    e -= 32768;
    if (e < 4096) {                         // W4 [128,32]
        int j = e & 7, L = (e >> 3) & 63, f = e >> 9;
        int kk = f & 3, nt = f >> 2;
        int k = kk * 32 + ((L >> 4) << 3) + j;
        W4p[e] = f2bf(W4[k * 32 + nt * 16 + (L & 15)]);
        return;
    }
    e -= 4096;
    if (e < 512) bias[e] = bih[e] + bhh[e];
}

// ---------------- loc/energy encoder: pure elementwise, writes feats kk=1,2 ----------
__global__ __launch_bounds__(256) void loc_kernel(
    const float* __restrict__ location, const float* __restrict__ energy,
    const float* __restrict__ Wl, const float* __restrict__ bl,
    const float* __restrict__ We, const float* __restrict__ be,
    short* __restrict__ featsb)
{
    __shared__ float C[160];    // Wl[64] | bl[32] | We[32] | be[32]
    const int tid = threadIdx.x;
    if (tid < 160) {
        float v;
        if (tid < 64)       v = Wl[tid];
        else if (tid < 96)  v = bl[tid - 64];
        else if (tid < 128) v = We[tid - 96];
        else                v = be[tid - 128];
        C[tid] = v;
    }
    __syncthreads();
    const int n = blockIdx.x * 64 + (tid >> 2);
    const int p = tid & 3;
    const float lx = location[(size_t)n * 2 + 0] * 0.1f;
    const float ly = location[(size_t)n * 2 + 1] * 0.1f;
    const float ev = energy[n] * (1.0f / 200.0f);
    const int t = n >> 12, b = n & 4095;
    const int grp = b >> 4, bi = b & 15;
    const int kk = 1 + (p >> 1);
    #pragma unroll
    for (int o = 0; o < 2; o++) {
        const int f0 = 32 + p * 16 + o * 8;        // feature base
        short8 v;
        #pragma unroll
        for (int j = 0; j < 8; j++) {
            const int f = f0 + j;
            float val;
            if (f < 64) { const int cix = f - 32; val = fmaf(lx, C[cix], fmaf(ly, C[32 + cix], C[64 + cix])); }
            else        { const int cix = f - 64; val = fmaf(ev, C[96 + cix], C[128 + cix]); }
            v[j] = f2bf(val);
        }
        const int Lhi = ((p & 1) << 1) + o;
        *(short8*)&featsb[FBASE(t, grp, kk) + (Lhi * 16 + bi) * 8] = v;
    }
}

// ---------------- persistent MFMA encoder: 256 blocks x 512 thr (8 waves) -------------
// All weights register-resident. Block streams 64 tiles of 32 samples.
// Activations in fragment order in LDS -> all hot reads conflict-free.
__global__ __launch_bounds__(512, 2) void enc_kernel(
    const float* __restrict__ image,
    const short* __restrict__ W1p, const float* __restrict__ b1,
    const short* __restrict__ W2p, const float* __restrict__ b2,
    const short* __restrict__ W3p, const float* __restrict__ b3,
    const short* __restrict__ W4p, const float* __restrict__ b4,
    short* __restrict__ featsb)
{
    __shared__ float Raw[2][800];                  // raw image tile (32 samples x 25)
    __shared__ __align__(16) short In[2 * 512];    // L1 input frags [st][64][8]
    __shared__ __align__(16) short AA[2 * 8 * 512];// act frags [st][kk][64][8]
    __shared__ __align__(16) short AB[2 * 8 * 512];
    const int tid  = threadIdx.x;
    const int lane = tid & 63, wv = tid >> 6;
    const int col  = lane & 15, quad = lane >> 4;

    // ---- register-resident weights & biases
    short8 w1r[2], w2r[2][8], w3r[8], w4r[4];
    #pragma unroll
    for (int i = 0; i < 2; i++)
        w1r[i] = *(const short8*)&W1p[((wv + 8 * i) * 64 + lane) * 8];
    #pragma unroll
    for (int i = 0; i < 2; i++)
        #pragma unroll
        for (int kk = 0; kk < 8; kk++)
            w2r[i][kk] = *(const short8*)&W2p[(((wv + 8 * i) * 8 + kk) * 64 + lane) * 8];
    #pragma unroll
    for (int kk = 0; kk < 8; kk++)
        w3r[kk] = *(const short8*)&W3p[((wv * 8 + kk) * 64 + lane) * 8];
    #pragma unroll
    for (int kk = 0; kk < 4; kk++)
        w4r[kk] = *(const short8*)&W4p[(((wv & 1) * 4 + kk) * 64 + lane) * 8];
    float4 b1r[2], b2r[2];
    #pragma unroll
    for (int i = 0; i < 2; i++) {
        b1r[i] = *(const float4*)(b1 + (wv + 8 * i) * 16 + quad * 4);
        b2r[i] = *(const float4*)(b2 + (wv + 8 * i) * 16 + quad * 4);
    }
    const float4 b3r = *(const float4*)(b3 + wv * 16 + quad * 4);
    const float4 b4r = *(const float4*)(b4 + (wv & 1) * 16 + quad * 4);

    const bool ld = tid < 400;
    float2 ir = {0.f, 0.f};
    // prologue: tile0 -> Raw[0]; prefetch tile1 into regs
    int tile = blockIdx.x;
    if (ld) {
        float2 t0 = *(const float2*)(image + (size_t)tile * 800 + 2 * tid);
        Raw[0][2 * tid] = t0.x; Raw[0][2 * tid + 1] = t0.y;
        ir = *(const float2*)(image + (size_t)(tile + 256) * 800 + 2 * tid);
    }
    __syncthreads();

    for (int it = 0; it < 64; it++) {
        const int cur = it & 1, nxt = cur ^ 1;
        tile = it * 256 + blockIdx.x;
        // fragify In from Raw[cur]
        if (tid < 128) {
            const int st = tid >> 6, L = tid & 63;
            const int s = st * 16 + (L & 15), kb = (L >> 4) * 8;
            short8 v;
            #pragma unroll
            for (int j = 0; j < 8; j++) {
                const int kx = kb + j;
                v[j] = (kx < 25) ? f2bf(Raw[cur][s * 25 + kx] * (1.0f / 255.0f)) : (short)0;
            }
            *(short8*)&In[(st * 64 + L) * 8] = v;
        }
        // write next tile's raw, prefetch tile+2
        if (ld && it + 1 < 64) { Raw[nxt][2 * tid] = ir.x; Raw[nxt][2 * tid + 1] = ir.y; }
        if (ld && it + 2 < 64)
            ir = *(const float2*)(image + (size_t)(tile + 512) * 800 + 2 * tid);
        __syncthreads();

        // ---- L1: K=32 -> 256 feats; wave owns nt {wv, wv+8}, st {0,1}
        {
            short8 bx[2];
            #pragma unroll
            for (int st = 0; st < 2; st++) bx[st] = *(const short8*)&In[(st * 64 + lane) * 8];
            #pragma unroll
            for (int i = 0; i < 2; i++) {
                const int nt = wv + 8 * i;
                #pragma unroll
                for (int st = 0; st < 2; st++) {
                    f32x4 acc = (f32x4){b1r[i].x, b1r[i].y, b1r[i].z, b1r[i].w};
                    acc = __builtin_amdgcn_mfma_f32_16x16x32_bf16(w1r[i], bx[st], acc, 0, 0, 0);
                    *(short4v*)&AA[((st * 8 + (nt >> 1)) * 64 + ((((nt & 1) << 1) + (quad >> 1)) << 4) + col) * 8 + (quad & 1) * 4]
                        = pack4relu(acc);
                }
            }
        }
        __syncthreads();

        // ---- L2: 256 -> 256 : AA -> AB
        {
            f32x4 acc[2][2];
            #pragma unroll
            for (int i = 0; i < 2; i++)
                #pragma unroll
                for (int st = 0; st < 2; st++)
                    acc[i][st] = (f32x4){b2r[i].x, b2r[i].y, b2r[i].z, b2r[i].w};
            #pragma unroll
            for (int kk = 0; kk < 8; kk++) {
                short8 bx[2];
                #pragma unroll
                for (int st = 0; st < 2; st++)
                    bx[st] = *(const short8*)&AA[((st * 8 + kk) * 64 + lane) * 8];
                #pragma unroll
                for (int i = 0; i < 2; i++)
                    #pragma unroll
                    for (int st = 0; st < 2; st++)
                        acc[i][st] = __builtin_amdgcn_mfma_f32_16x16x32_bf16(w2r[i][kk], bx[st], acc[i][st], 0, 0, 0);
            }
            #pragma unroll
            for (int i = 0; i < 2; i++) {
                const int nt = wv + 8 * i;
                #pragma unroll
                for (int st = 0; st < 2; st++)
                    *(short4v*)&AB[((st * 8 + (nt >> 1)) * 64 + ((((nt & 1) << 1) + (quad >> 1)) << 4) + col) * 8 + (quad & 1) * 4]
                        = pack4relu(acc[i][st]);
            }
        }
        __syncthreads();

        // ---- L3: 256 -> 128 : AB -> AA(kk 0..3); wave owns nt=wv
        {
            f32x4 acc[2];
            #pragma unroll
            for (int st = 0; st < 2; st++) acc[st] = (f32x4){b3r.x, b3r.y, b3r.z, b3r.w};
            #pragma unroll
            for (int kk = 0; kk < 8; kk++) {
                #pragma unroll
                for (int st = 0; st < 2; st++) {
                    const short8 bx = *(const short8*)&AB[((st * 8 + kk) * 64 + lane) * 8];
                    acc[st] = __builtin_amdgcn_mfma_f32_16x16x32_bf16(w3r[kk], bx, acc[st], 0, 0, 0);
                }
            }
            const int nt = wv;
            #pragma unroll
            for (int st = 0; st < 2; st++)
                *(short4v*)&AA[((st * 8 + (nt >> 1)) * 64 + ((((nt & 1) << 1) + (quad >> 1)) << 4) + col) * 8 + (quad & 1) * 4]
                    = pack4relu(acc[st]);
        }
        __syncthreads();

        // ---- L4: 128 -> 32; waves 0..3: (nt = wv&1, st = wv>>1) -> feats kk=0
        if (wv < 4) {
            const int nt = wv & 1, st = wv >> 1;
            f32x4 acc = (f32x4){b4r.x, b4r.y, b4r.z, b4r.w};
            #pragma unroll
            for (int kk = 0; kk < 4; kk++) {
                const short8 bx = *(const short8*)&AA[((st * 8 + kk) * 64 + lane) * 8];
                acc = __builtin_amdgcn_mfma_f32_16x16x32_bf16(w4r[kk], bx, acc, 0, 0, 0);
            }
            const int t4 = tile >> 7;
            const int grp = (tile & 127) * 2 + st;
            *(short4v*)&featsb[FBASE(t4, grp, 0) + (((nt << 1) + (quad >> 1)) * 16 + col) * 8 + (quad & 1) * 4]
                = pack4relu(acc);
        }
        __syncthreads();
    }
}

// ---------------- MFMA LSTM v3: register-resident weights, x direct from global ------
__global__ __launch_bounds__(512, 2) void lstm_kernel(
    const short* __restrict__ featsb, const int* __restrict__ done,
    const float* __restrict__ h0, const float* __restrict__ c0,
    const short* __restrict__ Wtp, const float* __restrict__ bias,
    const float* __restrict__ Wa, const float* __restrict__ ba,
    const float* __restrict__ Wc, const float* __restrict__ bc,
    float* __restrict__ out)
{
    __shared__ __align__(16) short Hb[2][4 * 64 * 8];   // h frags [buf][kk2][64][8] (8 KB)
    __shared__ __align__(16) short HW[4 * 64 * 8];      // head B-frags (4 KB)
    __shared__ float Ml[T_ * 16];                       // reset masks (8 KB)

    const int tid = threadIdx.x;
    const int r0 = blockIdx.x * 16;
    const int grp = r0 >> 4;
    const int lane = tid & 63;
    const int wv = tid >> 6;
    const int col = lane & 15;
    const int quad = lane >> 4;
    const int u = (wv << 4) + col;

    // ---- register-resident LSTM weights: wave wv owns n-tiles {wv, wv+8, wv+16, wv+24}
    short8 wtr[4][7];
    #pragma unroll
    for (int g = 0; g < 4; g++)
        #pragma unroll
        for (int kk = 0; kk < 7; kk++)
            wtr[g][kk] = *(const short8*)&Wtp[((size_t)((wv + 8 * g) * 7 + kk) * 64 + lane) * 8];

    // head weight B-frags -> LDS
    for (int idx = tid; idx < 4 * 64 * 8; idx += 512) {
        int j = idx & 7, L = (idx >> 3) & 63, kk2 = idx >> 9;
        int k = kk2 * 32 + ((L >> 4) << 3) + j;
        int n = L & 15;
        float v = (n < 6) ? Wa[k * 6 + n] : (n == 6 ? Wc[k] : 0.0f);
        HW[idx] = f2bf(v);
    }
    // reset masks for all T
    for (int idx = tid; idx < T_ * 16; idx += 512)
        Ml[idx] = 1.0f - (float)done[(size_t)(idx >> 4) * B_ + r0 + (idx & 15)];

    // init: c masked by done[0]; h0 UNMASKED into Hb[0] (mask applied at GEMM read)
    const int kk2h = wv >> 1;
    const int Lhi_h = ((wv & 1) << 1) | (col >> 3);
    const int jh = col & 7;
    f32x4 c;
    #pragma unroll
    for (int r = 0; r < 4; r++) {
        const int s = (quad << 2) + r;
        const float m = 1.0f - (float)done[r0 + s];
        c[r] = c0[(size_t)(r0 + s) * H_ + u] * m;
        Hb[0][(kk2h * 64 + Lhi_h * 16 + s) * 8 + jh] = f2bf(h0[(size_t)(r0 + s) * H_ + u]);
    }
    const float bi0 = bias[((wv +  0) << 4) + col];
    const float bi1 = bias[((wv +  8) << 4) + col];
    const float bi2 = bias[((wv + 16) << 4) + col];
    const float bi3 = bias[((wv + 24) << 4) + col];
    const float hb = (col < 6) ? ba[col] : (col == 6 ? bc[0] : 0.0f);

    // x prefetch pipeline, depth 2 (feats in A-frag order -> lane-linear loads)
    short8 xa[3], xb[3];
    #pragma unroll
    for (int kk = 0; kk < 3; kk++) {
        xa[kk] = *(const short8*)&featsb[FBASE(0, grp, kk) + lane * 8];
        xb[kk] = *(const short8*)&featsb[FBASE(1, grp, kk) + lane * 8];
    }
    __syncthreads();

    for (int t = 0; t < T_; t++) {
        const int cur = t & 1, nxt = cur ^ 1;
        const float mcol = Ml[t * 16 + col];
        f32x4 acc0 = {bi0, bi0, bi0, bi0};
        f32x4 acc1 = {bi1, bi1, bi1, bi1};
        f32x4 acc2 = {bi2, bi2, bi2, bi2};
        f32x4 acc3 = {bi3, bi3, bi3, bi3};
        #pragma unroll
        for (int kk = 0; kk < 7; kk++) {
            short8 af;
            if (kk < 3) af = xa[kk];
            else {
                af = *(const short8*)&Hb[cur][((kk - 3) * 64 + lane) * 8];
                if (mcol == 0.0f) af = (short8){0,0,0,0,0,0,0,0};
            }
            acc0 = __builtin_amdgcn_mfma_f32_16x16x32_bf16(af, wtr[0][kk], acc0, 0, 0, 0);
            acc1 = __builtin_amdgcn_mfma_f32_16x16x32_bf16(af, wtr[1][kk], acc1, 0, 0, 0);
            acc2 = __builtin_amdgcn_mfma_f32_16x16x32_bf16(af, wtr[2][kk], acc2, 0, 0, 0);
            acc3 = __builtin_amdgcn_mfma_f32_16x16x32_bf16(af, wtr[3][kk], acc3, 0, 0, 0);
        }
        // cell update; pre-mask c with m[t+1]; h stored UNMASKED
        float4 mn = {1.f, 1.f, 1.f, 1.f};
        if (t < T_ - 1) mn = *(const float4*)&Ml[(t + 1) * 16 + (quad << 2)];
        #pragma unroll
        for (int r = 0; r < 4; r++) {
            const float ig = fsig(acc0[r]);
            const float fg = fsig(acc1[r]);
            const float gg = ftanh(acc2[r]);
            const float og = fsig(acc3[r]);
            const float cn = fmaf(fg, c[r], ig * gg);
            const float h = og * ftanh(cn);
            c[r] = cn * ((&mn.x)[r]);
            Hb[nxt][(kk2h * 64 + Lhi_h * 16 + (quad << 2) + r) * 8 + jh] = f2bf(h);
        }
        // advance x pipeline
        #pragma unroll
        for (int kk = 0; kk < 3; kk++) xa[kk] = xb[kk];
        if (t + 2 < T_) {
            #pragma unroll
            for (int kk = 0; kk < 3; kk++)
                xb[kk] = *(const short8*)&featsb[FBASE(t + 2, grp, kk) + lane * 8];
        }
        __syncthreads();

        // wave 0: heads for step t from Hb[nxt] (unmasked h_t)
        if (wv == 0) {
            f32x4 ha = {hb, hb, hb, hb};
            #pragma unroll
            for (int kk2 = 0; kk2 < 4; kk2++) {
                const short8 hf = *(const short8*)&Hb[nxt][(kk2 * 64 + lane) * 8];
                const short8 wf = *(const short8*)&HW[(kk2 * 64 + lane) * 8];
                ha = __builtin_amdgcn_mfma_f32_16x16x32_bf16(hf, wf, ha, 0, 0, 0);
            }
            if (col < 7) {
                #pragma unroll
                for (int r = 0; r < 4; r++) {
                    const int s = (quad << 2) + r;
                    out[((size_t)t * B_ + r0 + s) * 7 + col] = ha[r];
                }
            }
        }
    }
}

extern "C" void kernel_launch(void* const* d_in, const int* in_sizes, int n_in,
                              void* d_out, int out_size, void* d_ws, size_t ws_size,
                              hipStream_t stream) {
    const float* image    = (const float*)d_in[0];
    const float* location = (const float*)d_in[1];
    const float* energy   = (const float*)d_in[2];
    const int*   done     = (const int*)d_in[3];
    const float* h0       = (const float*)d_in[4];
    const float* c0       = (const float*)d_in[5];
    const float* W1 = (const float*)d_in[6];   const float* b1 = (const float*)d_in[7];
    const float* W2 = (const float*)d_in[8];   const float* b2 = (const float*)d_in[9];
    const float* W3 = (const float*)d_in[10];  const float* b3 = (const float*)d_in[11];
    const float* W4 = (const float*)d_in[12];  const float* b4 = (const float*)d_in[13];
    const float* Wl = (const float*)d_in[14];  const float* bl = (const float*)d_in[15];
    const float* We = (const float*)d_in[16];  const float* be = (const float*)d_in[17];
    const float* Wih = (const float*)d_in[18]; const float* Whh = (const float*)d_in[19];
    const float* bih = (const float*)d_in[20]; const float* bhh = (const float*)d_in[21];
    const float* Wa = (const float*)d_in[22];  const float* ba = (const float*)d_in[23];
    const float* Wc = (const float*)d_in[24];  const float* bc = (const float*)d_in[25];

    char* ws = (char*)d_ws;
    short* Wtp   = (short*)ws;                     // 229376 B
    float* bias  = (float*)(ws + 229376);          // 2048 B
    short* W1p   = (short*)(ws + 231424);          // 16384 B
    short* W2p   = (short*)(ws + 247808);          // 131072 B
    short* W3p   = (short*)(ws + 378880);          // 65536 B
    short* W4p   = (short*)(ws + 444416);          // 8192 B
    short* featsb = (short*)(ws + 452608);         // N*96 bf16 (frag order) = 100663296 B
    float* out   = (float*)d_out;

    prep_kernel<<<882, 256, 0, stream>>>(Wih, Whh, bih, bhh, W1, W2, W3, W4,
                                         Wtp, bias, W1p, W2p, W3p, W4p);
    loc_kernel<<<N_ / 64, 256, 0, stream>>>(location, energy, Wl, bl, We, be, featsb);
    enc_kernel<<<256, 512, 0, stream>>>(image, W1p, b1, W2p, b2, W3p, b3, W4p, b4, featsb);
    lstm_kernel<<<B_ / 16, 512, 0, stream>>>(featsb, done, h0, c0, Wtp, bias,
                                             Wa, ba, Wc, bc, out);
}

// Round 6
// 427.595 us; speedup vs baseline: 9.3305x; 1.0418x over previous
//
#include <hip/hip_runtime.h>

#define T_ 128
#define B_ 4096
#define N_ (T_*B_)
#define H_ 128
#define FEAT_ 96
#define K_ 224
#define G4H_ 512
#define L2E 1.4426950408889634f

typedef __attribute__((ext_vector_type(8))) short short8;   // 8 bf16 = 4 VGPRs
typedef __attribute__((ext_vector_type(4))) short short4v;  // 4 bf16 = 2 VGPRs
typedef __attribute__((ext_vector_type(4))) float f32x4;

// sigmoid of PRE-SCALED gate (weights folded with log2e): 1/(1+2^-x)
__device__ __forceinline__ float sig2(float x) {
    return __builtin_amdgcn_rcpf(1.0f + __builtin_amdgcn_exp2f(-x));
}
// full tanh (for unscaled cell state)
__device__ __forceinline__ float ftanh(float x) {
    float e = __builtin_amdgcn_exp2f(-2.0f * L2E * x);
    return fmaf(2.0f, __builtin_amdgcn_rcpf(1.0f + e), -1.0f);
}
__device__ __forceinline__ short f2bf(float f) {
    unsigned u = __builtin_bit_cast(unsigned, f);
    u += 0x7fff + ((u >> 16) & 1);              // RNE
    return (short)(u >> 16);
}
__device__ __forceinline__ short4v pack4relu(const f32x4 a) {
    short4v v;
    v[0] = f2bf(fmaxf(a[0], 0.f)); v[1] = f2bf(fmaxf(a[1], 0.f));
    v[2] = f2bf(fmaxf(a[2], 0.f)); v[3] = f2bf(fmaxf(a[3], 0.f));
    return v;
}

// feats stored in MFMA-fragment order per 16-sample group:
// featsb[ ((t*256 + b/16)*3 + kk)*512 + L*8 + j ]
#define FBASE(t, grp, kk) ((((size_t)(t) * 256 + (grp)) * 3 + (kk)) * 512)

// ---------------- prep: pack all weights into bf16 MFMA-fragment order ----------------
// LSTM weights/bias pre-scaled: i,f,o gates by log2e; g gate by 2*log2e.
// W1 folded with 1/255 (image normalization).
__global__ __launch_bounds__(256) void prep_kernel(
    const float* __restrict__ Wih, const float* __restrict__ Whh,
    const float* __restrict__ bih, const float* __restrict__ bhh,
    const float* __restrict__ W1, const float* __restrict__ W2,
    const float* __restrict__ W3, const float* __restrict__ W4,
    short* __restrict__ Wtp, float* __restrict__ bias,
    short* __restrict__ W1p, short* __restrict__ W2p,
    short* __restrict__ W3p, short* __restrict__ W4p)
{
    int idx = blockIdx.x * 256 + threadIdx.x;
    if (idx < 114688) {                     // LSTM combined [224][512]
        int j = idx & 7, L = (idx >> 3) & 63, r = idx >> 9;
        int kk = r % 7, n = r / 7;
        int k = kk * 32 + ((L >> 4) << 3) + j;
        int g = (n << 4) + (L & 15);
        float v = (k < FEAT_) ? Wih[g * FEAT_ + k] : Whh[g * H_ + (k - FEAT_)];
        float s = (n >= 16 && n < 24) ? (2.0f * L2E) : L2E;   // g gate tiles: n 16..23
        Wtp[idx] = f2bf(v * s);
        return;
    }
    int e = idx - 114688;
    if (e < 8192) {                         // W1 [25,256] * (1/255), zero-pad k>=25
        int j = e & 7, L = (e >> 3) & 63, nt = e >> 9;
        int k = ((L >> 4) << 3) + j;
        int o = nt * 16 + (L & 15);
        W1p[e] = (k < 25) ? f2bf(W1[k * 256 + o] * (1.0f / 255.0f)) : (short)0;
        return;
    }
    e -= 8192;
    if (e < 65536) {                        // W2 [256,256]
        int j = e & 7, L = (e >> 3) & 63, f = e >> 9;
        int kk = f & 7, nt = f >> 3;
        int k = kk * 32 + ((L >> 4) << 3) + j;
        W2p[e] = f2bf(W2[k * 256 + nt * 16 + (L & 15)]);
        return;
    }
    e -= 65536;
    if (e < 32768) {                        // W3 [256,128]
        int j = e & 7, L = (e >> 3) & 63, f = e >> 9;
        int kk = f & 7, nt = f >> 3;
        int k = kk * 32 + ((L >> 4) << 3) + j;
        W3p[e] = f2bf(W3[k * 128 + nt * 16 + (L & 15)]);
        return;
    }
    e -= 32768;
    if (e < 4096) {                         // W4 [128,32]
        int j = e & 7, L = (e >> 3) & 63, f = e >> 9;
        int kk = f & 3, nt = f >> 2;
        int k = kk * 32 + ((L >> 4) << 3) + j;
        W4p[e] = f2bf(W4[k * 32 + nt * 16 + (L & 15)]);
        return;
    }
    e -= 4096;
    if (e < 512) {
        float s = ((e >> 7) == 2) ? (2.0f * L2E) : L2E;       // gate 2 = g
        bias[e] = (bih[e] + bhh[e]) * s;
    }
}

// ---------------- loc/energy encoder: pure elementwise, writes feats kk=1,2 ----------
__global__ __launch_bounds__(256) void loc_kernel(
    const float* __restrict__ location, const float* __restrict__ energy,
    const float* __restrict__ Wl, const float* __restrict__ bl,
    const float* __restrict__ We, const float* __restrict__ be,
    short* __restrict__ featsb)
{
    __shared__ float C[160];    // Wl[64] | bl[32] | We[32] | be[32]
    const int tid = threadIdx.x;
    if (tid < 160) {
        float v;
        if (tid < 64)       v = Wl[tid];
        else if (tid < 96)  v = bl[tid - 64];
        else if (tid < 128) v = We[tid - 96];
        else                v = be[tid - 128];
        C[tid] = v;
    }
    __syncthreads();
    const int n = blockIdx.x * 64 + (tid >> 2);
    const int p = tid & 3;
    const float lx = location[(size_t)n * 2 + 0] * 0.1f;
    const float ly = location[(size_t)n * 2 + 1] * 0.1f;
    const float ev = energy[n] * (1.0f / 200.0f);
    const int t = n >> 12, b = n & 4095;
    const int grp = b >> 4, bi = b & 15;
    const int kk = 1 + (p >> 1);
    #pragma unroll
    for (int o = 0; o < 2; o++) {
        const int f0 = 32 + p * 16 + o * 8;
        short8 v;
        #pragma unroll
        for (int j = 0; j < 8; j++) {
            const int f = f0 + j;
            float val;
            if (f < 64) { const int cix = f - 32; val = fmaf(lx, C[cix], fmaf(ly, C[32 + cix], C[64 + cix])); }
            else        { const int cix = f - 64; val = fmaf(ev, C[96 + cix], C[128 + cix]); }
            v[j] = f2bf(val);
        }
        const int Lhi = ((p & 1) << 1) + o;
        *(short8*)&featsb[FBASE(t, grp, kk) + (Lhi * 16 + bi) * 8] = v;
    }
}

// ---------------- persistent MFMA encoder: 256 blocks x 512 thr, 4 barriers/tile ------
// fragify of tile i+1 overlaps L4 of tile i on waves 4-7; L3 output in its own buffer.
__global__ __launch_bounds__(512, 2) void enc_kernel(
    const float* __restrict__ image,
    const short* __restrict__ W1p, const float* __restrict__ b1,
    const short* __restrict__ W2p, const float* __restrict__ b2,
    const short* __restrict__ W3p, const float* __restrict__ b3,
    const short* __restrict__ W4p, const float* __restrict__ b4,
    short* __restrict__ featsb)
{
    __shared__ float Raw[2][800];                  // raw image tile (32 samples x 25)
    __shared__ __align__(16) short In[2 * 512];    // L1 input frags [st][64][8]
    __shared__ __align__(16) short AA[2 * 8 * 512];// L1 out frags
    __shared__ __align__(16) short AB[2 * 8 * 512];// L2 out frags
    __shared__ __align__(16) short AC[2 * 4 * 512];// L3 out frags (own buffer)
    const int tid  = threadIdx.x;
    const int lane = tid & 63, wv = tid >> 6;
    const int col  = lane & 15, quad = lane >> 4;

    // ---- register-resident weights & biases
    short8 w1r[2], w2r[2][8], w3r[8], w4r[4];
    #pragma unroll
    for (int i = 0; i < 2; i++)
        w1r[i] = *(const short8*)&W1p[((wv + 8 * i) * 64 + lane) * 8];
    #pragma unroll
    for (int i = 0; i < 2; i++)
        #pragma unroll
        for (int kk = 0; kk < 8; kk++)
            w2r[i][kk] = *(const short8*)&W2p[(((wv + 8 * i) * 8 + kk) * 64 + lane) * 8];
    #pragma unroll
    for (int kk = 0; kk < 8; kk++)
        w3r[kk] = *(const short8*)&W3p[((wv * 8 + kk) * 64 + lane) * 8];
    #pragma unroll
    for (int kk = 0; kk < 4; kk++)
        w4r[kk] = *(const short8*)&W4p[(((wv & 1) * 4 + kk) * 64 + lane) * 8];
    float4 b1r[2], b2r[2];
    #pragma unroll
    for (int i = 0; i < 2; i++) {
        b1r[i] = *(const float4*)(b1 + (wv + 8 * i) * 16 + quad * 4);
        b2r[i] = *(const float4*)(b2 + (wv + 8 * i) * 16 + quad * 4);
    }
    const float4 b3r = *(const float4*)(b3 + wv * 16 + quad * 4);
    const float4 b4r = *(const float4*)(b4 + (wv & 1) * 16 + quad * 4);

    const bool ld = tid < 400;
    const int w4t = tid - 256;                     // fragify workers: waves 4-5
    float2 ir = {0.f, 0.f};

    // prologue: Raw[0] <- tile(blockIdx); fragify In; prefetch tile+256
    if (ld) {
        float2 t0 = *(const float2*)(image + (size_t)blockIdx.x * 800 + 2 * tid);
        Raw[0][2 * tid] = t0.x; Raw[0][2 * tid + 1] = t0.y;
        ir = *(const float2*)(image + (size_t)(blockIdx.x + 256) * 800 + 2 * tid);
    }
    __syncthreads();
    if (w4t >= 0 && w4t < 128) {
        const int st = w4t >> 6, L = w4t & 63;
        const int s = st * 16 + (L & 15), kb = (L >> 4) * 8;
        short8 v;
        #pragma unroll
        for (int j = 0; j < 8; j++) {
            const int kx = kb + j;
            v[j] = (kx < 25) ? f2bf(Raw[0][s * 25 + kx]) : (short)0;
        }
        *(short8*)&In[(st * 64 + L) * 8] = v;
    }

    for (int it = 0; it < 64; it++) {
        const int nxt = (it & 1) ^ 1;
        const int tile = it * 256 + blockIdx.x;
        // stage next tile's raw, prefetch tile+2
        if (ld && it + 1 < 64) { Raw[nxt][2 * tid] = ir.x; Raw[nxt][2 * tid + 1] = ir.y; }
        if (ld && it + 2 < 64)
            ir = *(const float2*)(image + (size_t)(tile + 512) * 800 + 2 * tid);
        __syncthreads();   // b0: In(tile) + Raw[nxt] visible

        // ---- L1: K=32 -> 256; wave owns nt {wv, wv+8}, st {0,1}
        {
            short8 bx[2];
            #pragma unroll
            for (int st = 0; st < 2; st++) bx[st] = *(const short8*)&In[(st * 64 + lane) * 8];
            #pragma unroll
            for (int i = 0; i < 2; i++) {
                const int nt = wv + 8 * i;
                #pragma unroll
                for (int st = 0; st < 2; st++) {
                    f32x4 acc = (f32x4){b1r[i].x, b1r[i].y, b1r[i].z, b1r[i].w};
                    acc = __builtin_amdgcn_mfma_f32_16x16x32_bf16(w1r[i], bx[st], acc, 0, 0, 0);
                    *(short4v*)&AA[((st * 8 + (nt >> 1)) * 64 + ((((nt & 1) << 1) + (quad >> 1)) << 4) + col) * 8 + (quad & 1) * 4]
                        = pack4relu(acc);
                }
            }
        }
        __syncthreads();   // b1

        // ---- L2: 256 -> 256 : AA -> AB
        {
            f32x4 acc[2][2];
            #pragma unroll
            for (int i = 0; i < 2; i++)
                #pragma unroll
                for (int st = 0; st < 2; st++)
                    acc[i][st] = (f32x4){b2r[i].x, b2r[i].y, b2r[i].z, b2r[i].w};
            #pragma unroll
            for (int kk = 0; kk < 8; kk++) {
                short8 bx[2];
                #pragma unroll
                for (int st = 0; st < 2; st++)
                    bx[st] = *(const short8*)&AA[((st * 8 + kk) * 64 + lane) * 8];
                #pragma unroll
                for (int i = 0; i < 2; i++)
                    #pragma unroll
                    for (int st = 0; st < 2; st++)
                        acc[i][st] = __builtin_amdgcn_mfma_f32_16x16x32_bf16(w2r[i][kk], bx[st], acc[i][st], 0, 0, 0);
            }
            #pragma unroll
            for (int i = 0; i < 2; i++) {
                const int nt = wv + 8 * i;
                #pragma unroll
                for (int st = 0; st < 2; st++)
                    *(short4v*)&AB[((st * 8 + (nt >> 1)) * 64 + ((((nt & 1) << 1) + (quad >> 1)) << 4) + col) * 8 + (quad & 1) * 4]
                        = pack4relu(acc[i][st]);
            }
        }
        __syncthreads();   // b2

        // ---- L3: 256 -> 128 : AB -> AC; wave owns nt=wv
        {
            f32x4 acc[2];
            #pragma unroll
            for (int st = 0; st < 2; st++) acc[st] = (f32x4){b3r.x, b3r.y, b3r.z, b3r.w};
            #pragma unroll
            for (int kk = 0; kk < 8; kk++) {
                #pragma unroll
                for (int st = 0; st < 2; st++) {
                    const short8 bx = *(const short8*)&AB[((st * 8 + kk) * 64 + lane) * 8];
                    acc[st] = __builtin_amdgcn_mfma_f32_16x16x32_bf16(w3r[kk], bx, acc[st], 0, 0, 0);
                }
            }
            const int nt = wv;
            #pragma unroll
            for (int st = 0; st < 2; st++)
                *(short4v*)&AC[((st * 4 + (nt >> 1)) * 64 + ((((nt & 1) << 1) + (quad >> 1)) << 4) + col) * 8 + (quad & 1) * 4]
                    = pack4relu(acc[st]);
        }
        __syncthreads();   // b3

        // ---- L4 (waves 0-3) || fragify tile it+1 (waves 4-5) — no trailing barrier
        if (wv < 4) {
            const int nt = wv & 1, st = wv >> 1;
            f32x4 acc = (f32x4){b4r.x, b4r.y, b4r.z, b4r.w};
            #pragma unroll
            for (int kk = 0; kk < 4; kk++) {
                const short8 bx = *(const short8*)&AC[((st * 4 + kk) * 64 + lane) * 8];
                acc = __builtin_amdgcn_mfma_f32_16x16x32_bf16(w4r[kk], bx, acc, 0, 0, 0);
            }
            const int t4 = tile >> 7;
            const int grp = (tile & 127) * 2 + st;
            *(short4v*)&featsb[FBASE(t4, grp, 0) + (((nt << 1) + (quad >> 1)) * 16 + col) * 8 + (quad & 1) * 4]
                = pack4relu(acc);
        } else if (w4t >= 0 && w4t < 128 && it + 1 < 64) {
            const int st = w4t >> 6, L = w4t & 63;
            const int s = st * 16 + (L & 15), kb = (L >> 4) * 8;
            short8 v;
            #pragma unroll
            for (int j = 0; j < 8; j++) {
                const int kx = kb + j;
                v[j] = (kx < 25) ? f2bf(Raw[nxt][s * 25 + kx]) : (short)0;
            }
            *(short8*)&In[(st * 64 + L) * 8] = v;
        }
    }
}

// ---------------- MFMA LSTM v4: unroll-2, round-robin heads, pre-scaled gates --------
__global__ __launch_bounds__(512, 2) void lstm_kernel(
    const short* __restrict__ featsb, const int* __restrict__ done,
    const float* __restrict__ h0, const float* __restrict__ c0,
    const short* __restrict__ Wtp, const float* __restrict__ bias,
    const float* __restrict__ Wa, const float* __restrict__ ba,
    const float* __restrict__ Wc, const float* __restrict__ bc,
    float* __restrict__ out)
{
    __shared__ __align__(16) short Hb[2][4 * 64 * 8];   // h frags [buf][kk2][64][8]
    __shared__ __align__(16) short HW[4 * 64 * 8];      // head B-frags
    __shared__ float Ml[T_ * 16];                       // reset masks

    const int tid = threadIdx.x;
    const int r0 = blockIdx.x * 16;
    const int grp = r0 >> 4;
    const int lane = tid & 63;
    const int wv = tid >> 6;
    const int col = lane & 15;
    const int quad = lane >> 4;
    const int u = (wv << 4) + col;

    // register-resident LSTM weights: wave wv owns n-tiles {wv, wv+8, wv+16, wv+24}
    short8 wtr[4][7];
    #pragma unroll
    for (int g = 0; g < 4; g++)
        #pragma unroll
        for (int kk = 0; kk < 7; kk++)
            wtr[g][kk] = *(const short8*)&Wtp[((size_t)((wv + 8 * g) * 7 + kk) * 64 + lane) * 8];

    // head weight B-frags -> LDS
    for (int idx = tid; idx < 4 * 64 * 8; idx += 512) {
        int j = idx & 7, L = (idx >> 3) & 63, kk2 = idx >> 9;
        int k = kk2 * 32 + ((L >> 4) << 3) + j;
        int n = L & 15;
        float v = (n < 6) ? Wa[k * 6 + n] : (n == 6 ? Wc[k] : 0.0f);
        HW[idx] = f2bf(v);
    }
    // reset masks for all T
    for (int idx = tid; idx < T_ * 16; idx += 512)
        Ml[idx] = 1.0f - (float)done[(size_t)(idx >> 4) * B_ + r0 + (idx & 15)];

    // init: c masked by done[0]; h0 UNMASKED into Hb[0] (mask applied at GEMM read)
    const int kk2h = wv >> 1;
    const int Lhi_h = ((wv & 1) << 1) | (col >> 3);
    const int jh = col & 7;
    f32x4 c;
    #pragma unroll
    for (int r = 0; r < 4; r++) {
        const int s = (quad << 2) + r;
        const float m = 1.0f - (float)done[r0 + s];
        c[r] = c0[(size_t)(r0 + s) * H_ + u] * m;
        Hb[0][(kk2h * 64 + Lhi_h * 16 + s) * 8 + jh] = f2bf(h0[(size_t)(r0 + s) * H_ + u]);
    }
    const float bi0 = bias[((wv +  0) << 4) + col];
    const float bi1 = bias[((wv +  8) << 4) + col];
    const float bi2 = bias[((wv + 16) << 4) + col];
    const float bi3 = bias[((wv + 24) << 4) + col];
    const float hb = (col < 6) ? ba[col] : (col == 6 ? bc[0] : 0.0f);

    // x prefetch: two register banks, no copies (t-loop unrolled by 2)
    short8 xa[3], xb[3];
    #pragma unroll
    for (int kk = 0; kk < 3; kk++) {
        xa[kk] = *(const short8*)&featsb[FBASE(0, grp, kk) + lane * 8];
        xb[kk] = *(const short8*)&featsb[FBASE(1, grp, kk) + lane * 8];
    }
    __syncthreads();

    auto STEP = [&](int t, int cur, short8* X) {
        const int nxt = cur ^ 1;
        const float mcol = Ml[t * 16 + col];
        f32x4 acc0 = {bi0, bi0, bi0, bi0};
        f32x4 acc1 = {bi1, bi1, bi1, bi1};
        f32x4 acc2 = {bi2, bi2, bi2, bi2};
        f32x4 acc3 = {bi3, bi3, bi3, bi3};
        #pragma unroll
        for (int kk = 0; kk < 7; kk++) {
            short8 af;
            if (kk < 3) af = X[kk];
            else {
                af = *(const short8*)&Hb[cur][((kk - 3) * 64 + lane) * 8];
                if (mcol == 0.0f) af = (short8){0,0,0,0,0,0,0,0};
            }
            acc0 = __builtin_amdgcn_mfma_f32_16x16x32_bf16(af, wtr[0][kk], acc0, 0, 0, 0);
            acc1 = __builtin_amdgcn_mfma_f32_16x16x32_bf16(af, wtr[1][kk], acc1, 0, 0, 0);
            acc2 = __builtin_amdgcn_mfma_f32_16x16x32_bf16(af, wtr[2][kk], acc2, 0, 0, 0);
            acc3 = __builtin_amdgcn_mfma_f32_16x16x32_bf16(af, wtr[3][kk], acc3, 0, 0, 0);
        }
        // cell update (gates pre-scaled by log2e / 2log2e); h stored UNMASKED
        float4 mn = {1.f, 1.f, 1.f, 1.f};
        if (t < T_ - 1) mn = *(const float4*)&Ml[(t + 1) * 16 + (quad << 2)];
        #pragma unroll
        for (int r = 0; r < 4; r++) {
            const float ig = sig2(acc0[r]);
            const float fg = sig2(acc1[r]);
            const float gt = fmaf(2.0f, sig2(acc2[r]), -1.0f);
            const float og = sig2(acc3[r]);
            const float cn = fmaf(fg, c[r], ig * gt);
            const float h = og * ftanh(cn);
            c[r] = cn * ((&mn.x)[r]);
            Hb[nxt][(kk2h * 64 + Lhi_h * 16 + (quad << 2) + r) * 8 + jh] = f2bf(h);
        }
        // reload this bank for t+2 (consumed 2 steps later)
        if (t + 2 < T_) {
            #pragma unroll
            for (int kk = 0; kk < 3; kk++)
                X[kk] = *(const short8*)&featsb[FBASE(t + 2, grp, kk) + lane * 8];
        }
        __syncthreads();

        // round-robin heads: wave (t&7) computes step t's heads from Hb[nxt]
        if (wv == (t & 7)) {
            f32x4 ha = {hb, hb, hb, hb};
            #pragma unroll
            for (int kk2 = 0; kk2 < 4; kk2++) {
                const short8 hf = *(const short8*)&Hb[nxt][(kk2 * 64 + lane) * 8];
                const short8 wf = *(const short8*)&HW[(kk2 * 64 + lane) * 8];
                ha = __builtin_amdgcn_mfma_f32_16x16x32_bf16(hf, wf, ha, 0, 0, 0);
            }
            if (col < 7) {
                #pragma unroll
                for (int r = 0; r < 4; r++) {
                    const int s = (quad << 2) + r;
                    out[((size_t)t * B_ + r0 + s) * 7 + col] = ha[r];
                }
            }
        }
    };

    for (int t = 0; t < T_; t += 2) {
        STEP(t, 0, xa);
        STEP(t + 1, 1, xb);
    }
}

extern "C" void kernel_launch(void* const* d_in, const int* in_sizes, int n_in,
                              void* d_out, int out_size, void* d_ws, size_t ws_size,
                              hipStream_t stream) {
    const float* image    = (const float*)d_in[0];
    const float* location = (const float*)d_in[1];
    const float* energy   = (const float*)d_in[2];
    const int*   done     = (const int*)d_in[3];
    const float* h0       = (const float*)d_in[4];
    const float* c0       = (const float*)d_in[5];
    const float* W1 = (const float*)d_in[6];   const float* b1 = (const float*)d_in[7];
    const float* W2 = (const float*)d_in[8];   const float* b2 = (const float*)d_in[9];
    const float* W3 = (const float*)d_in[10];  const float* b3 = (const float*)d_in[11];
    const float* W4 = (const float*)d_in[12];  const float* b4 = (const float*)d_in[13];
    const float* Wl = (const float*)d_in[14];  const float* bl = (const float*)d_in[15];
    const float* We = (const float*)d_in[16];  const float* be = (const float*)d_in[17];
    const float* Wih = (const float*)d_in[18]; const float* Whh = (const float*)d_in[19];
    const float* bih = (const float*)d_in[20]; const float* bhh = (const float*)d_in[21];
    const float* Wa = (const float*)d_in[22];  const float* ba = (const float*)d_in[23];
    const float* Wc = (const float*)d_in[24];  const float* bc = (const float*)d_in[25];

    char* ws = (char*)d_ws;
    short* Wtp   = (short*)ws;                     // 229376 B
    float* bias  = (float*)(ws + 229376);          // 2048 B
    short* W1p   = (short*)(ws + 231424);          // 16384 B
    short* W2p   = (short*)(ws + 247808);          // 131072 B
    short* W3p   = (short*)(ws + 378880);          // 65536 B
    short* W4p   = (short*)(ws + 444416);          // 8192 B
    short* featsb = (short*)(ws + 452608);         // N*96 bf16 (frag order)
    float* out   = (float*)d_out;

    prep_kernel<<<882, 256, 0, stream>>>(Wih, Whh, bih, bhh, W1, W2, W3, W4,
                                         Wtp, bias, W1p, W2p, W3p, W4p);
    loc_kernel<<<N_ / 64, 256, 0, stream>>>(location, energy, Wl, bl, We, be, featsb);
    enc_kernel<<<256, 512, 0, stream>>>(image, W1p, b1, W2p, b2, W3p, b3, W4p, b4, featsb);
    lstm_kernel<<<B_ / 16, 512, 0, stream>>>(featsb, done, h0, c0, Wtp, bias,
                                             Wa, ba, Wc, bc, out);
}